// Round 1
// baseline (2032.895 us; speedup 1.0000x reference)
//
#include <hip/hip_runtime.h>

#define AS1 __attribute__((address_space(1)))
#define AS3 __attribute__((address_space(3)))

typedef unsigned short u16;
typedef __attribute__((ext_vector_type(8))) __bf16 bf16x8;
typedef __attribute__((ext_vector_type(4))) float f32x4;

// Problem constants
#define BATCH   4
#define SEQLEN  2048
#define DMODEL  1024
#define DINNER  2048
#define DSTATE  16
#define ROWS    (BATCH * SEQLEN)   // 8192

__device__ __forceinline__ u16 f2bf(float f) {
  union { float f; unsigned u; } v; v.f = f;
  unsigned u = v.u;
  return (u16)((u + 0x7fffu + ((u >> 16) & 1u)) >> 16);   // RNE
}
__device__ __forceinline__ float bf2f(u16 s) {
  union { unsigned u; float f; } v; v.u = ((unsigned)s) << 16;
  return v.f;
}

// ---------------- cast f32 -> bf16 (4 elems/thread) ----------------
__global__ void cast_f32_bf16(const float* __restrict__ in, u16* __restrict__ out, int n4) {
  int i = blockIdx.x * blockDim.x + threadIdx.x;
  if (i >= n4) return;
  float4 v = ((const float4*)in)[i];
  ushort4 o;
  o.x = f2bf(v.x); o.y = f2bf(v.y); o.z = f2bf(v.z); o.w = f2bf(v.w);
  ((ushort4*)out)[i] = o;
}

// ---------------- transpose + cast: in f32 (R x C) -> out bf16 (C x R) ----------------
__global__ void transpose_cast(const float* __restrict__ in, u16* __restrict__ out, int R, int C) {
  __shared__ float tile[32][33];
  int x  = blockIdx.x * 32 + threadIdx.x;   // col in `in`
  int y0 = blockIdx.y * 32;
#pragma unroll
  for (int j = 0; j < 32; j += 8)
    tile[threadIdx.y + j][threadIdx.x] = in[(size_t)(y0 + threadIdx.y + j) * C + x];
  __syncthreads();
  int xo  = blockIdx.y * 32 + threadIdx.x;  // col in `out` (= row in `in`)
  int yo0 = blockIdx.x * 32;                // row in `out` (= col in `in`)
#pragma unroll
  for (int j = 0; j < 32; j += 8)
    out[(size_t)(yo0 + threadIdx.y + j) * R + xo] = f2bf(tile[threadIdx.x][threadIdx.y + j]);
}

// ---------------- bf16 MFMA GEMM: C(MxN) = A(MxK) * Bt(NxK)^T ----------------
// 128x128 tile, BK=32, 4 waves (2x2), each wave 64x64 via 4x4 16x16x32 mfma.
// EPI: 0 = store bf16, 1 = softplus(v + bias[col]) -> f32, 2 = store f32
template<int EPI>
__launch_bounds__(256, 2)
__global__ void gemm_bf16(const u16* __restrict__ A, const u16* __restrict__ Bt,
                          void* __restrict__ outp, const float* __restrict__ bias,
                          int M, int N, int K, int gm) {
  __shared__ u16 ldsA[128 * 32];
  __shared__ u16 ldsB[128 * 32];
  const int nb  = gridDim.x;
  const int bid = blockIdx.x;
  const int swz = (bid & 7) * (nb >> 3) + (bid >> 3);   // XCD swizzle (nb % 8 == 0)
  const int bm = swz % gm, bn = swz / gm;

  const int t = threadIdx.x;
  const int wave = t >> 6, lane = t & 63;
  const int wm = wave >> 1, wn = wave & 1;
  const int lhi = lane >> 4, llo = lane & 15;
  const size_t bm0 = (size_t)bm * 128, bn0 = (size_t)bn * 128;

  f32x4 acc[4][4] = {};

  for (int k0 = 0; k0 < K; k0 += 32) {
#pragma unroll
    for (int c = 0; c < 2; ++c) {
      int e = (c * 256 + t) * 8;          // element offset into 128x32 tile
      int row = e >> 5, col = e & 31;
      const u16* gA = A  + (bm0 + row) * K + (k0 + col);
      const u16* gB = Bt + (bn0 + row) * K + (k0 + col);
      __builtin_amdgcn_global_load_lds((const AS1 void*)gA,
          (AS3 void*)(ldsA + c * 2048 + wave * 512), 16, 0, 0);
      __builtin_amdgcn_global_load_lds((const AS1 void*)gB,
          (AS3 void*)(ldsB + c * 2048 + wave * 512), 16, 0, 0);
    }
    __syncthreads();

    bf16x8 af[4], bfr[4];
#pragma unroll
    for (int m = 0; m < 4; ++m)
      af[m] = *(const bf16x8*)(const void*)(ldsA + (wm * 64 + m * 16 + llo) * 32 + lhi * 8);
#pragma unroll
    for (int n = 0; n < 4; ++n)
      bfr[n] = *(const bf16x8*)(const void*)(ldsB + (wn * 64 + n * 16 + llo) * 32 + lhi * 8);
#pragma unroll
    for (int m = 0; m < 4; ++m)
#pragma unroll
      for (int n = 0; n < 4; ++n)
        acc[m][n] = __builtin_amdgcn_mfma_f32_16x16x32_bf16(af[m], bfr[n], acc[m][n], 0, 0, 0);
    __syncthreads();
  }

#pragma unroll
  for (int m = 0; m < 4; ++m) {
#pragma unroll
    for (int n = 0; n < 4; ++n) {
      int col = (int)bn0 + wn * 64 + n * 16 + llo;
#pragma unroll
      for (int r = 0; r < 4; ++r) {
        int row = (int)bm0 + wm * 64 + m * 16 + lhi * 4 + r;
        float v = acc[m][n][r];
        size_t idx = (size_t)row * N + col;
        if (EPI == 0) {
          ((u16*)outp)[idx] = f2bf(v);
        } else if (EPI == 1) {
          float xb = v + bias[col];
          ((float*)outp)[idx] = (xb > 20.f) ? xb : log1pf(__expf(xb));  // softplus
        } else {
          ((float*)outp)[idx] = v;
        }
      }
    }
  }
}

// ---------------- causal depthwise conv (K=4) + SiLU ----------------
// xz bf16 (ROWS x 4096), xc = cols [0,2048). xs bf16 (ROWS x 2048).
__global__ void conv_silu(const u16* __restrict__ xz, const float* __restrict__ w,
                          const float* __restrict__ cb, u16* __restrict__ xs, int total) {
  int idx = blockIdx.x * 256 + threadIdx.x;
  if (idx >= total) return;
  int d = idx & (DINNER - 1);
  int l = (idx >> 11) & (SEQLEN - 1);
  int b = idx >> 22;
  float4 wv = ((const float4*)w)[d];
  float acc = cb[d];
#pragma unroll
  for (int k = 0; k < 4; ++k) {
    int li = l - 3 + k;
    if (li >= 0) {
      float xv = bf2f(xz[(size_t)(b * SEQLEN + li) * (2 * DINNER) + d]);
      acc = fmaf((&wv.x)[k], xv, acc);
    }
  }
  float s = acc / (1.f + __expf(-acc));   // silu
  xs[(size_t)idx] = f2bf(s);
}

// ---------------- x-projection: xproj(ROWS x 32) = xs(ROWS x 2048) @ Wx(2048 x 32) ----------------
__global__ void xproj_kernel(const u16* __restrict__ xs, const float* __restrict__ Wx,
                             float* __restrict__ outp) {
  int c = threadIdx.x & 31;
  int rloc = threadIdx.x >> 5;            // 0..7
  int row = blockIdx.x * 8 + rloc;
  const u16* xr = xs + (size_t)row * DINNER;
  float acc = 0.f;
#pragma unroll 4
  for (int k = 0; k < DINNER; ++k)
    acc = fmaf(bf2f(xr[k]), Wx[k * 32 + c], acc);
  outp[(size_t)row * 32 + c] = acc;
}

// ---------------- selective scan: one thread per (b, d, s) ----------------
// block 256 = 16 d x 16 s; grid = BATCH * (DINNER/16) = 512.
__global__ void scan_kernel(const float* __restrict__ delta, const u16* __restrict__ xs,
                            const float* __restrict__ xproj, const u16* __restrict__ xz,
                            const float* __restrict__ A_log, const float* __restrict__ Dp,
                            u16* __restrict__ yg) {
  int s = threadIdx.x & 15;
  int dloc = threadIdx.x >> 4;            // 0..15
  int b = blockIdx.x >> 7;
  int dblk = blockIdx.x & 127;
  int d = dblk * 16 + dloc;
  float A  = -__expf(A_log[d * DSTATE + s]);
  float Dv = Dp[d];
  float h = 0.f;
  int row0 = b * SEQLEN;
#pragma unroll 2
  for (int l = 0; l < SEQLEN; ++l) {
    size_t row = (size_t)(row0 + l);
    float dt = delta[row * DINNER + d];
    float xv = bf2f(xs[row * DINNER + d]);
    float bv = xproj[row * 32 + s];
    float cv = xproj[row * 32 + 16 + s];
    float dA = fmaf(A, dt, 1.f);
    h = fmaf(h, dA, bv * (dt * xv));
    float yp = h * cv;
    yp += __shfl_xor(yp, 8, 16);
    yp += __shfl_xor(yp, 4, 16);
    yp += __shfl_xor(yp, 2, 16);
    yp += __shfl_xor(yp, 1, 16);
    if (s == 0) {
      float z = bf2f(xz[row * (2 * DINNER) + DINNER + d]);
      float y = yp + Dv * xv;
      float g = z / (1.f + __expf(-z));
      yg[row * DINNER + d] = f2bf(y * g);
    }
  }
}

extern "C" void kernel_launch(void* const* d_in, const int* in_sizes, int n_in,
                              void* d_out, int out_size, void* d_ws, size_t ws_size,
                              hipStream_t stream) {
  const float* x       = (const float*)d_in[0];
  const float* W_in    = (const float*)d_in[1];
  const float* conv_w  = (const float*)d_in[2];
  const float* conv_b  = (const float*)d_in[3];
  const float* W_xproj = (const float*)d_in[4];
  const float* W_dt    = (const float*)d_in[5];
  const float* b_dt    = (const float*)d_in[6];
  const float* A_log   = (const float*)d_in[7];
  const float* D_param = (const float*)d_in[8];
  const float* W_out   = (const float*)d_in[9];
  float* out = (float*)d_out;

  char* ws = (char*)d_ws;
  const size_t MB = 1ull << 20;
  u16*   x_bf  = (u16*)(ws);              // 16 MB   [dead after GEMM1]
  u16*   WinT  = (u16*)(ws + 16 * MB);    //  8 MB   [dead after GEMM1]
  u16*   WdtT  = (u16*)(ws + 24 * MB);    //  8 MB   [dead after GEMM2]
  u16*   xz_bf = (u16*)(ws + 32 * MB);    // 64 MB   [live through scan]
  u16*   xs_bf = (u16*)(ws + 96 * MB);    // 32 MB   [live through scan]
  float* delta = (float*)(ws + 128 * MB); // 64 MB
  float* xpj   = (float*)(ws + 192 * MB); //  1 MB
  u16*   WoutT = (u16*)(ws + 193 * MB);   //  4 MB
  u16*   yg    = (u16*)(ws);              // 32 MB, aliases x_bf/WinT/WdtT (dead by then)

  dim3 tb(32, 8);

  // 1) casts / weight transposes
  cast_f32_bf16<<<(ROWS * DMODEL / 4 + 255) / 256, 256, 0, stream>>>(x, x_bf, ROWS * DMODEL / 4);
  transpose_cast<<<dim3((2 * DINNER) / 32, DMODEL / 32), tb, 0, stream>>>(W_in, WinT, DMODEL, 2 * DINNER);
  transpose_cast<<<dim3(DINNER / 32, DINNER / 32), tb, 0, stream>>>(W_dt, WdtT, DINNER, DINNER);
  transpose_cast<<<dim3(DMODEL / 32, DINNER / 32), tb, 0, stream>>>(W_out, WoutT, DINNER, DMODEL);

  // 2) xz = x @ W_in            (8192 x 4096, K=1024) -> bf16
  gemm_bf16<0><<<(ROWS / 128) * ((2 * DINNER) / 128), 256, 0, stream>>>(
      x_bf, WinT, xz_bf, nullptr, ROWS, 2 * DINNER, DMODEL, ROWS / 128);

  // 3) xs = silu(causal_conv(xc) + conv_b) -> bf16
  conv_silu<<<(ROWS * DINNER) / 256, 256, 0, stream>>>(xz_bf, conv_w, conv_b, xs_bf, ROWS * DINNER);

  // 4) delta = softplus(xs @ W_dt + b_dt) (8192 x 2048, K=2048) -> f32
  gemm_bf16<1><<<(ROWS / 128) * (DINNER / 128), 256, 0, stream>>>(
      xs_bf, WdtT, delta, b_dt, ROWS, DINNER, DINNER, ROWS / 128);

  // 5) [Bs|Cs] = xs @ W_xproj   (8192 x 32) -> f32
  xproj_kernel<<<ROWS / 8, 256, 0, stream>>>(xs_bf, W_xproj, xpj);

  // 6) selective scan + D-skip + silu(z) gate -> yg bf16
  scan_kernel<<<BATCH * (DINNER / 16), 256, 0, stream>>>(delta, xs_bf, xpj, xz_bf, A_log, D_param, yg);

  // 7) out = yg @ W_out         (8192 x 1024, K=2048) -> f32
  gemm_bf16<2><<<(ROWS / 128) * (DMODEL / 128), 256, 0, stream>>>(
      yg, WoutT, out, nullptr, ROWS, DMODEL, DINNER, ROWS / 128);
}

// Round 2
// 568.072 us; speedup vs baseline: 3.5786x; 3.5786x over previous
//
#include <hip/hip_runtime.h>

#define AS1 __attribute__((address_space(1)))
#define AS3 __attribute__((address_space(3)))

typedef unsigned short u16;
typedef __attribute__((ext_vector_type(8))) __bf16 bf16x8;
typedef __attribute__((ext_vector_type(8))) unsigned short u16x8;
typedef __attribute__((ext_vector_type(4))) float f32x4;

// Problem constants
#define BATCH   4
#define SEQLEN  2048
#define DMODEL  1024
#define DINNER  2048
#define DSTATE  16
#define ROWS    (BATCH * SEQLEN)   // 8192

__device__ __forceinline__ u16 f2bf(float f) {
  union { float f; unsigned u; } v; v.f = f;
  unsigned u = v.u;
  return (u16)((u + 0x7fffu + ((u >> 16) & 1u)) >> 16);   // RNE
}
__device__ __forceinline__ float bf2f(u16 s) {
  union { unsigned u; float f; } v; v.u = ((unsigned)s) << 16;
  return v.f;
}

// ---------------- cast f32 -> bf16 (4 elems/thread) ----------------
__global__ void cast_f32_bf16(const float* __restrict__ in, u16* __restrict__ out, int n4) {
  int i = blockIdx.x * blockDim.x + threadIdx.x;
  if (i >= n4) return;
  float4 v = ((const float4*)in)[i];
  ushort4 o;
  o.x = f2bf(v.x); o.y = f2bf(v.y); o.z = f2bf(v.z); o.w = f2bf(v.w);
  ((ushort4*)out)[i] = o;
}

// ---------------- transpose + cast: in f32 (R x C) -> out bf16 (C x R) ----------------
__global__ void transpose_cast(const float* __restrict__ in, u16* __restrict__ out, int R, int C) {
  __shared__ float tile[32][33];
  int x  = blockIdx.x * 32 + threadIdx.x;   // col in `in`
  int y0 = blockIdx.y * 32;
#pragma unroll
  for (int j = 0; j < 32; j += 8)
    tile[threadIdx.y + j][threadIdx.x] = in[(size_t)(y0 + threadIdx.y + j) * C + x];
  __syncthreads();
  int xo  = blockIdx.y * 32 + threadIdx.x;  // col in `out` (= row in `in`)
  int yo0 = blockIdx.x * 32;                // row in `out` (= col in `in`)
#pragma unroll
  for (int j = 0; j < 32; j += 8)
    out[(size_t)(yo0 + threadIdx.y + j) * R + xo] = f2bf(tile[threadIdx.x][threadIdx.y + j]);
}

// ---------------- bf16 MFMA GEMM: C(MxN) = A(MxK) * Bt(NxK)^T ----------------
// 128x128 tile, BK=32, 4 waves (2x2), each wave 64x64 via 4x4 16x16x32 mfma.
// EPI: 0 = store bf16, 1 = softplus(v + bias[col]) -> f32, 2 = store f32
template<int EPI>
__launch_bounds__(256, 2)
__global__ void gemm_bf16(const u16* __restrict__ A, const u16* __restrict__ Bt,
                          void* __restrict__ outp, const float* __restrict__ bias,
                          int M, int N, int K, int gm) {
  __shared__ u16 ldsA[128 * 32];
  __shared__ u16 ldsB[128 * 32];
  const int nb  = gridDim.x;
  const int bid = blockIdx.x;
  const int swz = (bid & 7) * (nb >> 3) + (bid >> 3);   // XCD swizzle (nb % 8 == 0)
  const int bm = swz % gm, bn = swz / gm;

  const int t = threadIdx.x;
  const int wave = t >> 6, lane = t & 63;
  const int wm = wave >> 1, wn = wave & 1;
  const int lhi = lane >> 4, llo = lane & 15;
  const size_t bm0 = (size_t)bm * 128, bn0 = (size_t)bn * 128;

  f32x4 acc[4][4] = {};

  for (int k0 = 0; k0 < K; k0 += 32) {
#pragma unroll
    for (int c = 0; c < 2; ++c) {
      int e = (c * 256 + t) * 8;          // element offset into 128x32 tile
      int row = e >> 5, col = e & 31;
      const u16* gA = A  + (bm0 + row) * K + (k0 + col);
      const u16* gB = Bt + (bn0 + row) * K + (k0 + col);
      __builtin_amdgcn_global_load_lds((const AS1 void*)gA,
          (AS3 void*)(ldsA + c * 2048 + wave * 512), 16, 0, 0);
      __builtin_amdgcn_global_load_lds((const AS1 void*)gB,
          (AS3 void*)(ldsB + c * 2048 + wave * 512), 16, 0, 0);
    }
    __syncthreads();

    bf16x8 af[4], bfr[4];
#pragma unroll
    for (int m = 0; m < 4; ++m)
      af[m] = *(const bf16x8*)(const void*)(ldsA + (wm * 64 + m * 16 + llo) * 32 + lhi * 8);
#pragma unroll
    for (int n = 0; n < 4; ++n)
      bfr[n] = *(const bf16x8*)(const void*)(ldsB + (wn * 64 + n * 16 + llo) * 32 + lhi * 8);
#pragma unroll
    for (int m = 0; m < 4; ++m)
#pragma unroll
      for (int n = 0; n < 4; ++n)
        acc[m][n] = __builtin_amdgcn_mfma_f32_16x16x32_bf16(af[m], bfr[n], acc[m][n], 0, 0, 0);
    __syncthreads();
  }

#pragma unroll
  for (int m = 0; m < 4; ++m) {
#pragma unroll
    for (int n = 0; n < 4; ++n) {
      int col = (int)bn0 + wn * 64 + n * 16 + llo;
#pragma unroll
      for (int r = 0; r < 4; ++r) {
        int row = (int)bm0 + wm * 64 + m * 16 + lhi * 4 + r;
        float v = acc[m][n][r];
        size_t idx = (size_t)row * N + col;
        if (EPI == 0) {
          ((u16*)outp)[idx] = f2bf(v);
        } else if (EPI == 1) {
          float xb = v + bias[col];
          ((float*)outp)[idx] = (xb > 20.f) ? xb : log1pf(__expf(xb));  // softplus
        } else {
          ((float*)outp)[idx] = v;
        }
      }
    }
  }
}

// ---------------- causal depthwise conv (K=4) + SiLU ----------------
// xz bf16 (ROWS x 4096), xc = cols [0,2048). xs bf16 (ROWS x 2048).
__global__ void conv_silu(const u16* __restrict__ xz, const float* __restrict__ w,
                          const float* __restrict__ cb, u16* __restrict__ xs, int total) {
  int idx = blockIdx.x * 256 + threadIdx.x;
  if (idx >= total) return;
  int d = idx & (DINNER - 1);
  int l = (idx >> 11) & (SEQLEN - 1);
  int b = idx >> 22;
  float4 wv = ((const float4*)w)[d];
  float acc = cb[d];
#pragma unroll
  for (int k = 0; k < 4; ++k) {
    int li = l - 3 + k;
    if (li >= 0) {
      float xv = bf2f(xz[(size_t)(b * SEQLEN + li) * (2 * DINNER) + d]);
      acc = fmaf((&wv.x)[k], xv, acc);
    }
  }
  float s = acc / (1.f + __expf(-acc));   // silu
  xs[(size_t)idx] = f2bf(s);
}

// ---------------- x-projection: xproj(ROWS x 32) = xs(ROWS x 2048) @ Wx(2048 x 32) ----------------
// One row per block; 256 threads = 32 cols x 8 K-partitions; bf16x8 vector loads.
__global__ void xproj_kernel(const u16* __restrict__ xs, const float* __restrict__ Wx,
                             float* __restrict__ outp) {
  __shared__ float part[256];
  int row = blockIdx.x;
  int tid = threadIdx.x;
  int c = tid & 31, kp = tid >> 5;        // kp in [0,8)
  const u16* xr = xs + (size_t)row * DINNER + kp * 256;
  const float* wp = Wx + (size_t)(kp * 256) * 32 + c;
  float acc = 0.f;
#pragma unroll 4
  for (int kk = 0; kk < 32; ++kk) {
    u16x8 xv = *(const u16x8*)(const void*)(xr + kk * 8);
#pragma unroll
    for (int j = 0; j < 8; ++j)
      acc = fmaf(bf2f(xv[j]), wp[(kk * 8 + j) * 32], acc);
  }
  part[tid] = acc;
  __syncthreads();
  if (tid < 32) {
    float s = 0.f;
#pragma unroll
    for (int p = 0; p < 8; ++p) s += part[p * 32 + tid];
    outp[(size_t)row * 32 + tid] = s;
  }
}

// ---------------- chunked selective scan ----------------
// Block = (batch b, 16 d-channels). 512 threads = 16 d (low bits, coalesced) x 32 chunks.
// Each thread holds all 16 states in registers. 3 phases:
//   1) per-chunk local scan from 0 -> carry (P = prod dA, H = local end state) in LDS
//   2) 256 threads serially compose the 32 chunk carries -> h_begin per chunk (in LDS)
//   3) re-scan each chunk from h_begin; y = <h,C> + D*x; gate with silu(z); store bf16
#define SC_NC 32           // chunks
#define SC_CL (SEQLEN / SC_NC)  // 64 steps per chunk
#define SC_DG 16           // d-channels per block

__launch_bounds__(512, 2)
__global__ void scan_chunked(const float* __restrict__ delta, const u16* __restrict__ xs,
                             const float* __restrict__ xproj, const u16* __restrict__ xz,
                             const float* __restrict__ A_log, const float* __restrict__ Dp,
                             u16* __restrict__ yg) {
  __shared__ float cP[SC_NC][SC_DG][DSTATE];   // 32 KB (later reused as h_begin)
  __shared__ float cH[SC_NC][SC_DG][DSTATE];   // 32 KB
  const int tid = threadIdx.x;
  const int dl = tid & 15, ck = tid >> 4;      // d-lane, chunk
  const int b = blockIdx.x >> 7, dblk = blockIdx.x & 127;
  const int d = dblk * SC_DG + dl;
  const int r0 = b * SEQLEN + ck * SC_CL;

  float A[DSTATE];
  {
    const f32x4* ap = (const f32x4*)(A_log + (size_t)d * DSTATE);
#pragma unroll
    for (int q = 0; q < 4; ++q) {
      f32x4 a = ap[q];
#pragma unroll
      for (int j = 0; j < 4; ++j) A[q * 4 + j] = -__expf(a[j]);
    }
  }

  // ---- pass 1: local scan, accumulate carry (P, H) ----
  float P[DSTATE], Hh[DSTATE];
#pragma unroll
  for (int s = 0; s < DSTATE; ++s) { P[s] = 1.f; Hh[s] = 0.f; }
#pragma unroll 2
  for (int l = 0; l < SC_CL; ++l) {
    size_t row = (size_t)(r0 + l);
    float dt = delta[row * DINNER + d];
    float xv = bf2f(xs[row * DINNER + d]);
    float dtx = dt * xv;
    const f32x4* bp = (const f32x4*)(xproj + row * 32);
    f32x4 Bq[4];
#pragma unroll
    for (int q = 0; q < 4; ++q) Bq[q] = bp[q];
#pragma unroll
    for (int s = 0; s < DSTATE; ++s) {
      float dA = fmaf(A[s], dt, 1.f);
      P[s] *= dA;
      Hh[s] = fmaf(Hh[s], dA, Bq[s >> 2][s & 3] * dtx);
    }
  }
#pragma unroll
  for (int s = 0; s < DSTATE; ++s) { cP[ck][dl][s] = P[s]; cH[ck][dl][s] = Hh[s]; }
  __syncthreads();

  // ---- pass 2: serial carry composition over 32 chunks (coalesced LDS) ----
  if (tid < SC_DG * DSTATE) {
    int s2 = tid & 15, dd = tid >> 4;
    float h = 0.f;
    for (int c = 0; c < SC_NC; ++c) {
      float p = cP[c][dd][s2], hh = cH[c][dd][s2];
      cP[c][dd][s2] = h;                 // h_begin for chunk c
      h = fmaf(p, h, hh);
    }
  }
  __syncthreads();

  // ---- pass 3: re-scan from h_begin, emit gated output ----
  float h[DSTATE];
#pragma unroll
  for (int s = 0; s < DSTATE; ++s) h[s] = cP[ck][dl][s];
  const float Dv = Dp[d];
#pragma unroll 2
  for (int l = 0; l < SC_CL; ++l) {
    size_t row = (size_t)(r0 + l);
    float dt = delta[row * DINNER + d];
    float xv = bf2f(xs[row * DINNER + d]);
    float dtx = dt * xv;
    const f32x4* bp = (const f32x4*)(xproj + row * 32);
    f32x4 Bq[4], Cq[4];
#pragma unroll
    for (int q = 0; q < 4; ++q) { Bq[q] = bp[q]; Cq[q] = bp[q + 4]; }
    float yp = 0.f;
#pragma unroll
    for (int s = 0; s < DSTATE; ++s) {
      float dA = fmaf(A[s], dt, 1.f);
      h[s] = fmaf(h[s], dA, Bq[s >> 2][s & 3] * dtx);
      yp = fmaf(h[s], Cq[s >> 2][s & 3], yp);
    }
    float z = bf2f(xz[row * (2 * DINNER) + DINNER + d]);
    float y = yp + Dv * xv;
    float g = z / (1.f + __expf(-z));
    yg[row * DINNER + d] = f2bf(y * g);
  }
}

extern "C" void kernel_launch(void* const* d_in, const int* in_sizes, int n_in,
                              void* d_out, int out_size, void* d_ws, size_t ws_size,
                              hipStream_t stream) {
  const float* x       = (const float*)d_in[0];
  const float* W_in    = (const float*)d_in[1];
  const float* conv_w  = (const float*)d_in[2];
  const float* conv_b  = (const float*)d_in[3];
  const float* W_xproj = (const float*)d_in[4];
  const float* W_dt    = (const float*)d_in[5];
  const float* b_dt    = (const float*)d_in[6];
  const float* A_log   = (const float*)d_in[7];
  const float* D_param = (const float*)d_in[8];
  const float* W_out   = (const float*)d_in[9];
  float* out = (float*)d_out;

  char* ws = (char*)d_ws;
  const size_t MB = 1ull << 20;
  u16*   x_bf  = (u16*)(ws);              // 16 MB   [dead after GEMM1]
  u16*   WinT  = (u16*)(ws + 16 * MB);    //  8 MB   [dead after GEMM1]
  u16*   WdtT  = (u16*)(ws + 24 * MB);    //  8 MB   [dead after GEMM2]
  u16*   xz_bf = (u16*)(ws + 32 * MB);    // 64 MB   [live through scan]
  u16*   xs_bf = (u16*)(ws + 96 * MB);    // 32 MB   [live through scan]
  float* delta = (float*)(ws + 128 * MB); // 64 MB
  float* xpj   = (float*)(ws + 192 * MB); //  1 MB
  u16*   WoutT = (u16*)(ws + 193 * MB);   //  4 MB
  u16*   yg    = (u16*)(ws);              // 32 MB, aliases x_bf/WinT/WdtT (dead by then)

  dim3 tb(32, 8);

  // 1) casts / weight transposes
  cast_f32_bf16<<<(ROWS * DMODEL / 4 + 255) / 256, 256, 0, stream>>>(x, x_bf, ROWS * DMODEL / 4);
  transpose_cast<<<dim3((2 * DINNER) / 32, DMODEL / 32), tb, 0, stream>>>(W_in, WinT, DMODEL, 2 * DINNER);
  transpose_cast<<<dim3(DINNER / 32, DINNER / 32), tb, 0, stream>>>(W_dt, WdtT, DINNER, DINNER);
  transpose_cast<<<dim3(DMODEL / 32, DINNER / 32), tb, 0, stream>>>(W_out, WoutT, DINNER, DMODEL);

  // 2) xz = x @ W_in            (8192 x 4096, K=1024) -> bf16
  gemm_bf16<0><<<(ROWS / 128) * ((2 * DINNER) / 128), 256, 0, stream>>>(
      x_bf, WinT, xz_bf, nullptr, ROWS, 2 * DINNER, DMODEL, ROWS / 128);

  // 3) xs = silu(causal_conv(xc) + conv_b) -> bf16
  conv_silu<<<(ROWS * DINNER) / 256, 256, 0, stream>>>(xz_bf, conv_w, conv_b, xs_bf, ROWS * DINNER);

  // 4) delta = softplus(xs @ W_dt + b_dt) (8192 x 2048, K=2048) -> f32
  gemm_bf16<1><<<(ROWS / 128) * (DINNER / 128), 256, 0, stream>>>(
      xs_bf, WdtT, delta, b_dt, ROWS, DINNER, DINNER, ROWS / 128);

  // 5) [Bs|Cs] = xs @ W_xproj   (8192 x 32) -> f32
  xproj_kernel<<<ROWS, 256, 0, stream>>>(xs_bf, W_xproj, xpj);

  // 6) chunked selective scan + D-skip + silu(z) gate -> yg bf16
  scan_chunked<<<BATCH * (DINNER / SC_DG), 512, 0, stream>>>(
      delta, xs_bf, xpj, xz_bf, A_log, D_param, yg);

  // 7) out = yg @ W_out         (8192 x 1024, K=2048) -> f32
  gemm_bf16<2><<<(ROWS / 128) * (DMODEL / 128), 256, 0, stream>>>(
      yg, WoutT, out, nullptr, ROWS, DMODEL, DINNER, ROWS / 128);
}

// Round 3
// 561.884 us; speedup vs baseline: 3.6180x; 1.0110x over previous
//
#include <hip/hip_runtime.h>

#define AS1 __attribute__((address_space(1)))
#define AS3 __attribute__((address_space(3)))

typedef unsigned short u16;
typedef __attribute__((ext_vector_type(8))) __bf16 bf16x8;
typedef __attribute__((ext_vector_type(8))) unsigned short u16x8;
typedef __attribute__((ext_vector_type(4))) float f32x4;

// Problem constants
#define BATCH   4
#define SEQLEN  2048
#define DMODEL  1024
#define DINNER  2048
#define DSTATE  16
#define ROWS    (BATCH * SEQLEN)   // 8192

__device__ __forceinline__ u16 f2bf(float f) {
  union { float f; unsigned u; } v; v.f = f;
  unsigned u = v.u;
  return (u16)((u + 0x7fffu + ((u >> 16) & 1u)) >> 16);   // RNE
}
__device__ __forceinline__ float bf2f(u16 s) {
  union { unsigned u; float f; } v; v.u = ((unsigned)s) << 16;
  return v.f;
}

// ---------------- cast f32 -> bf16 (4 elems/thread) ----------------
__global__ void cast_f32_bf16(const float* __restrict__ in, u16* __restrict__ out, int n4) {
  int i = blockIdx.x * blockDim.x + threadIdx.x;
  if (i >= n4) return;
  float4 v = ((const float4*)in)[i];
  ushort4 o;
  o.x = f2bf(v.x); o.y = f2bf(v.y); o.z = f2bf(v.z); o.w = f2bf(v.w);
  ((ushort4*)out)[i] = o;
}

// ---------------- transpose + cast: in f32 (R x C) -> out bf16 (C x R) ----------------
__global__ void transpose_cast(const float* __restrict__ in, u16* __restrict__ out, int R, int C) {
  __shared__ float tile[32][33];
  int x  = blockIdx.x * 32 + threadIdx.x;   // col in `in`
  int y0 = blockIdx.y * 32;
#pragma unroll
  for (int j = 0; j < 32; j += 8)
    tile[threadIdx.y + j][threadIdx.x] = in[(size_t)(y0 + threadIdx.y + j) * C + x];
  __syncthreads();
  int xo  = blockIdx.y * 32 + threadIdx.x;  // col in `out` (= row in `in`)
  int yo0 = blockIdx.x * 32;                // row in `out` (= col in `in`)
#pragma unroll
  for (int j = 0; j < 32; j += 8)
    out[(size_t)(yo0 + threadIdx.y + j) * R + xo] = f2bf(tile[threadIdx.x][threadIdx.y + j]);
}

// ---------------- 256x256 8-phase bf16 MFMA GEMM: C = A(MxK) * Bt(NxK)^T ----------------
// 512 threads = 8 waves (2M x 4N); per-wave 128x64 output; BK=64; 128 KB dbuf LDS.
// T2 xor-swizzle (pre-swizzled global source + swizzled ds_read, linear LDS dest),
// T3/T4 phase schedule with counted vmcnt, T5 setprio around MFMA clusters.
// EPI: 0 = store bf16, 1 = softplus(v + bias[col]) -> f32, 2 = store f32
template<int EPI>
__launch_bounds__(512, 1)
__global__ void gemm256(const u16* __restrict__ A, const u16* __restrict__ Bt,
                        void* __restrict__ outp, const float* __restrict__ bias,
                        int M, int N, int K, int gm) {
  extern __shared__ u16 lds[];   // [2 buf][A 16384 | B 16384] u16 = 128 KB
  const int nb  = gridDim.x;
  const int bid = blockIdx.x;
  const int swz = (bid & 7) * (nb >> 3) + (bid >> 3);   // XCD swizzle (nb % 8 == 0)
  const int bm = swz % gm, bn = swz / gm;

  const int tid  = threadIdx.x;
  const int wave = tid >> 6, lane = tid & 63;
  const int wm = wave >> 2, wn = wave & 3;              // 2 x 4 wave grid
  const int llo = lane & 15, lhi = lane >> 4;
  const size_t bm0 = (size_t)bm * 256, bn0 = (size_t)bn * 256;
  const int NT = K >> 6;

  // staging precompute: 4 A chunks + 4 B chunks of 16 B per thread per K-tile
  // chunk ch = c*512 + tid; row = ch>>3; pre-swizzled source col = ((ch&7)^(row&7))<<3
  const u16* gA[4]; const u16* gB[4];
#pragma unroll
  for (int c = 0; c < 4; ++c) {
    int ch = c * 512 + tid;
    int row = ch >> 3;
    int scol = ((ch & 7) ^ (row & 7)) << 3;
    gA[c] = A  + (bm0 + row) * (size_t)K + scol;
    gB[c] = Bt + (bn0 + row) * (size_t)K + scol;
  }

  // swizzled read offsets: phys_byte = row*128 + ((kk*64 + lhi*16) ^ ((llo&7)<<4))
  const int mask = (llo & 7) << 4;
  const int ko[2] = { ((0 * 64 + lhi * 16) ^ mask) >> 1, ((1 * 64 + lhi * 16) ^ mask) >> 1 };

#define STAGE(t, bsel)                                                              \
  do {                                                                              \
    int k0_ = (t) << 6;                                                             \
    u16* la_ = lds + (bsel) * 32768;                                                \
    u16* lb_ = la_ + 16384;                                                         \
    _Pragma("unroll")                                                               \
    for (int c = 0; c < 4; ++c)                                                     \
      __builtin_amdgcn_global_load_lds((const AS1 void*)(gA[c] + k0_),              \
          (AS3 void*)(la_ + c * 4096 + wave * 512), 16, 0, 0);                      \
    _Pragma("unroll")                                                               \
    for (int c = 0; c < 4; ++c)                                                     \
      __builtin_amdgcn_global_load_lds((const AS1 void*)(gB[c] + k0_),              \
          (AS3 void*)(lb_ + c * 4096 + wave * 512), 16, 0, 0);                      \
  } while (0)

  f32x4 acc[8][4] = {};

  STAGE(0, 0);
  STAGE(1, 1);
  asm volatile("s_waitcnt vmcnt(8)" ::: "memory");
  __builtin_amdgcn_s_barrier();

  for (int t = 0; t < NT; ++t) {
    const int cur = t & 1;
    const u16* la = lds + cur * 32768;
    const u16* lb = la + 16384;
    bf16x8 bfr[4];
#pragma unroll
    for (int sub = 0; sub < 4; ++sub) {
      const int kk = sub >> 1, mh = sub & 1;
      if (mh == 0) {
#pragma unroll
        for (int n = 0; n < 4; ++n)
          bfr[n] = *(const bf16x8*)(const void*)(lb + (wn * 64 + n * 16 + llo) * 64 + ko[kk]);
      }
      bf16x8 af[4];
#pragma unroll
      for (int m = 0; m < 4; ++m)
        af[m] = *(const bf16x8*)(const void*)(la + (wm * 128 + mh * 64 + m * 16 + llo) * 64 + ko[kk]);
      __builtin_amdgcn_s_barrier();
      __builtin_amdgcn_s_setprio(1);
#pragma unroll
      for (int m = 0; m < 4; ++m)
#pragma unroll
        for (int n = 0; n < 4; ++n)
          acc[mh * 4 + m][n] = __builtin_amdgcn_mfma_f32_16x16x32_bf16(af[m], bfr[n], acc[mh * 4 + m][n], 0, 0, 0);
      __builtin_amdgcn_s_setprio(0);
      __builtin_amdgcn_s_barrier();
    }
    // prefetch tile t+2 into the buffer we just finished reading (all waves past barrier)
    if (t + 2 < NT) {
      STAGE(t + 2, cur);
      asm volatile("s_waitcnt vmcnt(8)" ::: "memory");   // tile t+1 landed; t+2 stays in flight
    } else {
      asm volatile("s_waitcnt vmcnt(0)" ::: "memory");   // tail drain
    }
    __builtin_amdgcn_s_barrier();
  }
#undef STAGE

  // epilogue: C mapping col = n*16+llo, row = am*16 + lhi*4 + r
#pragma unroll
  for (int am = 0; am < 8; ++am) {
    const int mh = am >> 2, m = am & 3;
    const int rowb = (int)bm0 + wm * 128 + mh * 64 + m * 16 + lhi * 4;
#pragma unroll
    for (int n = 0; n < 4; ++n) {
      const int col = (int)bn0 + wn * 64 + n * 16 + llo;
#pragma unroll
      for (int r = 0; r < 4; ++r) {
        float v = acc[am][n][r];
        size_t idx = (size_t)(rowb + r) * N + col;
        if (EPI == 0) {
          ((u16*)outp)[idx] = f2bf(v);
        } else if (EPI == 1) {
          float xb = v + bias[col];
          ((float*)outp)[idx] = (xb > 20.f) ? xb : log1pf(__expf(xb));  // softplus
        } else {
          ((float*)outp)[idx] = v;
        }
      }
    }
  }
}

// ---------------- causal depthwise conv (K=4) + SiLU ----------------
__global__ void conv_silu(const u16* __restrict__ xz, const float* __restrict__ w,
                          const float* __restrict__ cb, u16* __restrict__ xs, int total) {
  int idx = blockIdx.x * 256 + threadIdx.x;
  if (idx >= total) return;
  int d = idx & (DINNER - 1);
  int l = (idx >> 11) & (SEQLEN - 1);
  int b = idx >> 22;
  float4 wv = ((const float4*)w)[d];
  float acc = cb[d];
#pragma unroll
  for (int k = 0; k < 4; ++k) {
    int li = l - 3 + k;
    if (li >= 0) {
      float xv = bf2f(xz[(size_t)(b * SEQLEN + li) * (2 * DINNER) + d]);
      acc = fmaf((&wv.x)[k], xv, acc);
    }
  }
  float s = acc / (1.f + __expf(-acc));   // silu
  xs[(size_t)idx] = f2bf(s);
}

// ---------------- x-projection: xproj(ROWS x 32) = xs(ROWS x 2048) @ Wx(2048 x 32) ----------------
__global__ void xproj_kernel(const u16* __restrict__ xs, const float* __restrict__ Wx,
                             float* __restrict__ outp) {
  __shared__ float part[256];
  int row = blockIdx.x;
  int tid = threadIdx.x;
  int c = tid & 31, kp = tid >> 5;        // kp in [0,8)
  const u16* xr = xs + (size_t)row * DINNER + kp * 256;
  const float* wp = Wx + (size_t)(kp * 256) * 32 + c;
  float acc = 0.f;
#pragma unroll 4
  for (int kk = 0; kk < 32; ++kk) {
    u16x8 xv = *(const u16x8*)(const void*)(xr + kk * 8);
#pragma unroll
    for (int j = 0; j < 8; ++j)
      acc = fmaf(bf2f(xv[j]), wp[(kk * 8 + j) * 32], acc);
  }
  part[tid] = acc;
  __syncthreads();
  if (tid < 32) {
    float s = 0.f;
#pragma unroll
    for (int p = 0; p < 8; ++p) s += part[p * 32 + tid];
    outp[(size_t)row * 32 + tid] = s;
  }
}

// ---------------- chunked selective scan ----------------
#define SC_NC 32                // chunks
#define SC_CL (SEQLEN / SC_NC)  // 64 steps per chunk
#define SC_DG 16                // d-channels per block

__launch_bounds__(512, 2)
__global__ void scan_chunked(const float* __restrict__ delta, const u16* __restrict__ xs,
                             const float* __restrict__ xproj, const u16* __restrict__ xz,
                             const float* __restrict__ A_log, const float* __restrict__ Dp,
                             u16* __restrict__ yg) {
  __shared__ float cP[SC_NC][SC_DG][DSTATE];   // 32 KB (later reused as h_begin)
  __shared__ float cH[SC_NC][SC_DG][DSTATE];   // 32 KB
  const int tid = threadIdx.x;
  const int dl = tid & 15, ck = tid >> 4;      // d-lane, chunk
  const int b = blockIdx.x >> 7, dblk = blockIdx.x & 127;
  const int d = dblk * SC_DG + dl;
  const int r0 = b * SEQLEN + ck * SC_CL;

  float A[DSTATE];
  {
    const f32x4* ap = (const f32x4*)(A_log + (size_t)d * DSTATE);
#pragma unroll
    for (int q = 0; q < 4; ++q) {
      f32x4 a = ap[q];
#pragma unroll
      for (int j = 0; j < 4; ++j) A[q * 4 + j] = -__expf(a[j]);
    }
  }

  // ---- pass 1: local scan, accumulate carry (P, H) ----
  float P[DSTATE], Hh[DSTATE];
#pragma unroll
  for (int s = 0; s < DSTATE; ++s) { P[s] = 1.f; Hh[s] = 0.f; }
#pragma unroll 2
  for (int l = 0; l < SC_CL; ++l) {
    size_t row = (size_t)(r0 + l);
    float dt = delta[row * DINNER + d];
    float xv = bf2f(xs[row * DINNER + d]);
    float dtx = dt * xv;
    const f32x4* bp = (const f32x4*)(xproj + row * 32);
    f32x4 Bq[4];
#pragma unroll
    for (int q = 0; q < 4; ++q) Bq[q] = bp[q];
#pragma unroll
    for (int s = 0; s < DSTATE; ++s) {
      float dA = fmaf(A[s], dt, 1.f);
      P[s] *= dA;
      Hh[s] = fmaf(Hh[s], dA, Bq[s >> 2][s & 3] * dtx);
    }
  }
#pragma unroll
  for (int s = 0; s < DSTATE; ++s) { cP[ck][dl][s] = P[s]; cH[ck][dl][s] = Hh[s]; }
  __syncthreads();

  // ---- pass 2: serial carry composition over 32 chunks ----
  if (tid < SC_DG * DSTATE) {
    int s2 = tid & 15, dd = tid >> 4;
    float h = 0.f;
    for (int c = 0; c < SC_NC; ++c) {
      float p = cP[c][dd][s2], hh = cH[c][dd][s2];
      cP[c][dd][s2] = h;                 // h_begin for chunk c
      h = fmaf(p, h, hh);
    }
  }
  __syncthreads();

  // ---- pass 3: re-scan from h_begin, emit gated output ----
  float h[DSTATE];
#pragma unroll
  for (int s = 0; s < DSTATE; ++s) h[s] = cP[ck][dl][s];
  const float Dv = Dp[d];
#pragma unroll 2
  for (int l = 0; l < SC_CL; ++l) {
    size_t row = (size_t)(r0 + l);
    float dt = delta[row * DINNER + d];
    float xv = bf2f(xs[row * DINNER + d]);
    float dtx = dt * xv;
    const f32x4* bp = (const f32x4*)(xproj + row * 32);
    f32x4 Bq[4], Cq[4];
#pragma unroll
    for (int q = 0; q < 4; ++q) { Bq[q] = bp[q]; Cq[q] = bp[q + 4]; }
    float yp = 0.f;
#pragma unroll
    for (int s = 0; s < DSTATE; ++s) {
      float dA = fmaf(A[s], dt, 1.f);
      h[s] = fmaf(h[s], dA, Bq[s >> 2][s & 3] * dtx);
      yp = fmaf(h[s], Cq[s >> 2][s & 3], yp);
    }
    float z = bf2f(xz[row * (2 * DINNER) + DINNER + d]);
    float y = yp + Dv * xv;
    float g = z / (1.f + __expf(-z));
    yg[row * DINNER + d] = f2bf(y * g);
  }
}

extern "C" void kernel_launch(void* const* d_in, const int* in_sizes, int n_in,
                              void* d_out, int out_size, void* d_ws, size_t ws_size,
                              hipStream_t stream) {
  const float* x       = (const float*)d_in[0];
  const float* W_in    = (const float*)d_in[1];
  const float* conv_w  = (const float*)d_in[2];
  const float* conv_b  = (const float*)d_in[3];
  const float* W_xproj = (const float*)d_in[4];
  const float* W_dt    = (const float*)d_in[5];
  const float* b_dt    = (const float*)d_in[6];
  const float* A_log   = (const float*)d_in[7];
  const float* D_param = (const float*)d_in[8];
  const float* W_out   = (const float*)d_in[9];
  float* out = (float*)d_out;

  char* ws = (char*)d_ws;
  const size_t MB = 1ull << 20;
  u16*   x_bf  = (u16*)(ws);              // 16 MB   [dead after GEMM1]
  u16*   WinT  = (u16*)(ws + 16 * MB);    //  8 MB   [dead after GEMM1]
  u16*   WdtT  = (u16*)(ws + 24 * MB);    //  8 MB   [dead after GEMM2]
  u16*   xz_bf = (u16*)(ws + 32 * MB);    // 64 MB   [live through scan]
  u16*   xs_bf = (u16*)(ws + 96 * MB);    // 32 MB   [live through scan]
  float* delta = (float*)(ws + 128 * MB); // 64 MB
  float* xpj   = (float*)(ws + 192 * MB); //  1 MB
  u16*   WoutT = (u16*)(ws + 193 * MB);   //  4 MB
  u16*   yg    = (u16*)(ws);              // 32 MB, aliases x_bf/WinT/WdtT (dead by then)

  // allow 128 KB dynamic LDS for the 8-phase GEMM
  hipFuncSetAttribute((const void*)gemm256<0>, hipFuncAttributeMaxDynamicSharedMemorySize, 131072);
  hipFuncSetAttribute((const void*)gemm256<1>, hipFuncAttributeMaxDynamicSharedMemorySize, 131072);
  hipFuncSetAttribute((const void*)gemm256<2>, hipFuncAttributeMaxDynamicSharedMemorySize, 131072);

  dim3 tb(32, 8);

  // 1) casts / weight transposes
  cast_f32_bf16<<<(ROWS * DMODEL / 4 + 255) / 256, 256, 0, stream>>>(x, x_bf, ROWS * DMODEL / 4);
  transpose_cast<<<dim3((2 * DINNER) / 32, DMODEL / 32), tb, 0, stream>>>(W_in, WinT, DMODEL, 2 * DINNER);
  transpose_cast<<<dim3(DINNER / 32, DINNER / 32), tb, 0, stream>>>(W_dt, WdtT, DINNER, DINNER);
  transpose_cast<<<dim3(DMODEL / 32, DINNER / 32), tb, 0, stream>>>(W_out, WoutT, DINNER, DMODEL);

  // 2) xz = x @ W_in            (8192 x 4096, K=1024) -> bf16
  gemm256<0><<<(ROWS / 256) * ((2 * DINNER) / 256), 512, 131072, stream>>>(
      x_bf, WinT, xz_bf, nullptr, ROWS, 2 * DINNER, DMODEL, ROWS / 256);

  // 3) xs = silu(causal_conv(xc) + conv_b) -> bf16
  conv_silu<<<(ROWS * DINNER) / 256, 256, 0, stream>>>(xz_bf, conv_w, conv_b, xs_bf, ROWS * DINNER);

  // 4) delta = softplus(xs @ W_dt + b_dt) (8192 x 2048, K=2048) -> f32
  gemm256<1><<<(ROWS / 256) * (DINNER / 256), 512, 131072, stream>>>(
      xs_bf, WdtT, delta, b_dt, ROWS, DINNER, DINNER, ROWS / 256);

  // 5) [Bs|Cs] = xs @ W_xproj   (8192 x 32) -> f32
  xproj_kernel<<<ROWS, 256, 0, stream>>>(xs_bf, W_xproj, xpj);

  // 6) chunked selective scan + D-skip + silu(z) gate -> yg bf16
  scan_chunked<<<BATCH * (DINNER / SC_DG), 512, 0, stream>>>(
      delta, xs_bf, xpj, xz_bf, A_log, D_param, yg);

  // 7) out = yg @ W_out         (8192 x 1024, K=2048) -> f32
  gemm256<2><<<(ROWS / 256) * (DMODEL / 256), 512, 131072, stream>>>(
      yg, WoutT, out, nullptr, ROWS, DMODEL, DINNER, ROWS / 256);
}

// Round 4
// 513.021 us; speedup vs baseline: 3.9626x; 1.0952x over previous
//
#include <hip/hip_runtime.h>

#define AS1 __attribute__((address_space(1)))
#define AS3 __attribute__((address_space(3)))

typedef unsigned short u16;
typedef __attribute__((ext_vector_type(8))) __bf16 bf16x8;
typedef __attribute__((ext_vector_type(8))) unsigned short u16x8;
typedef __attribute__((ext_vector_type(4))) float f32x4;

// Problem constants
#define BATCH   4
#define SEQLEN  2048
#define DMODEL  1024
#define DINNER  2048
#define DSTATE  16
#define ROWS    (BATCH * SEQLEN)   // 8192

__device__ __forceinline__ u16 f2bf(float f) {
  union { float f; unsigned u; } v; v.f = f;
  unsigned u = v.u;
  return (u16)((u + 0x7fffu + ((u >> 16) & 1u)) >> 16);   // RNE
}
__device__ __forceinline__ float bf2f(u16 s) {
  union { unsigned u; float f; } v; v.u = ((unsigned)s) << 16;
  return v.f;
}

// ---------------- cast f32 -> bf16 (4 elems/thread) ----------------
__global__ void cast_f32_bf16(const float* __restrict__ in, u16* __restrict__ out, int n4) {
  int i = blockIdx.x * blockDim.x + threadIdx.x;
  if (i >= n4) return;
  float4 v = ((const float4*)in)[i];
  ushort4 o;
  o.x = f2bf(v.x); o.y = f2bf(v.y); o.z = f2bf(v.z); o.w = f2bf(v.w);
  ((ushort4*)out)[i] = o;
}

// ---------------- transpose + cast: in f32 (R x C) -> out bf16 (C x R) ----------------
__global__ void transpose_cast(const float* __restrict__ in, u16* __restrict__ out, int R, int C) {
  __shared__ float tile[32][33];
  int x  = blockIdx.x * 32 + threadIdx.x;
  int y0 = blockIdx.y * 32;
#pragma unroll
  for (int j = 0; j < 32; j += 8)
    tile[threadIdx.y + j][threadIdx.x] = in[(size_t)(y0 + threadIdx.y + j) * C + x];
  __syncthreads();
  int xo  = blockIdx.y * 32 + threadIdx.x;
  int yo0 = blockIdx.x * 32;
#pragma unroll
  for (int j = 0; j < 32; j += 8)
    out[(size_t)(yo0 + threadIdx.y + j) * R + xo] = f2bf(tile[threadIdx.x][threadIdx.y + j]);
}

// ---------------- 256xBN 8-phase bf16 MFMA GEMM: C = A(MxK) * Bt(NxK)^T ----------------
// 512 threads = 8 waves (2M x 4N); per-wave 128 x (BN/4); BK=64; double-buffered LDS.
// Fine interleave: each phase = {ds_reads, stage one 2-chunk group, barrier,
// setprio(1), 16/8 MFMA, setprio(0), [counted vmcnt at phases 4/8], barrier}.
// T2 swizzle: linear LDS dest + pre-swizzled global source + swizzled ds_read.
// XCD 2D super-tile block mapping (rr x cc blocks per XCD) for L2 locality.
// EPI: 0 = store bf16, 1 = softplus(v + bias[col]) -> bf16, 2 = store f32
template<int EPI, int BN_>
__launch_bounds__(512, 1)
__global__ void gemm8p(const u16* __restrict__ A, const u16* __restrict__ Bt,
                       void* __restrict__ outp, const float* __restrict__ bias,
                       int M, int N, int K, int gn, int rr, int cc) {
  constexpr int NF   = BN_ / 64;        // n-frags per wave (4 or 2)
  constexpr int BCH  = BN_ / 64;        // B chunks of 64 rows (4 or 2)
  constexpr int ASZ  = 256 * 64;        // u16 per A tile
  constexpr int BSZ  = BN_ * 64;
  constexpr int BUFS = ASZ + BSZ;       // u16 per buffer
  extern __shared__ u16 lds[];

  const int xcd = blockIdx.x & 7, kb = blockIdx.x >> 3;
  const int tpr = gn / cc;              // xcd-tiles per tile-row
  const int bm  = (xcd / tpr) * rr + kb / cc;
  const int bn  = (xcd % tpr) * cc + kb % cc;

  const int tid  = threadIdx.x;
  const int wave = tid >> 6, lane = tid & 63;
  const int wm = wave >> 2, wn = wave & 3;
  const int llo = lane & 15, lhi = lane >> 4;
  const size_t bm0 = (size_t)bm * 256, bn0 = (size_t)bn * BN_;
  const int NT = K >> 6;

  // staging source pointers (pre-swizzled column slot so LDS stays linear)
  const u16* gA[4];
#pragma unroll
  for (int ch = 0; ch < 4; ++ch) {
    int row  = ch * 64 + (tid >> 3);
    int scol = ((tid & 7) ^ (row & 7)) << 3;
    gA[ch] = A + (bm0 + row) * (size_t)K + scol;
  }
  const u16* gB[BCH];
#pragma unroll
  for (int ch = 0; ch < BCH; ++ch) {
    int row  = ch * 64 + (tid >> 3);
    int scol = ((tid & 7) ^ (row & 7)) << 3;
    gB[ch] = Bt + (bn0 + row) * (size_t)K + scol;
  }

  // swizzled LDS read offsets (u16 units)
  const int mask = (llo & 7) << 4;
  const int ko[2] = { ((0 + lhi * 16) ^ mask) >> 1, ((64 + lhi * 16) ^ mask) >> 1 };

#define SGA(t, bsel, ch) __builtin_amdgcn_global_load_lds(                       \
    (const AS1 void*)(gA[ch] + ((size_t)(t) << 6)),                              \
    (AS3 void*)(lds + (bsel) * BUFS + (ch) * 4096 + wave * 512), 16, 0, 0)
#define SGB(t, bsel, ch) __builtin_amdgcn_global_load_lds(                       \
    (const AS1 void*)(gB[ch] + ((size_t)(t) << 6)),                              \
    (AS3 void*)(lds + (bsel) * BUFS + ASZ + (ch) * 4096 + wave * 512), 16, 0, 0)

  f32x4 acc[8][NF] = {};
  bf16x8 bfr[2][NF];

#define PHASE(la_, lb_, MH, KK, RDB, STG, WC)                                    \
  {                                                                              \
    bf16x8 af[4];                                                                \
    _Pragma("unroll") for (int m = 0; m < 4; ++m)                                \
      af[m] = *(const bf16x8*)(const void*)((la_) + (wm*128 + MH*64 + m*16 + llo)*64 + ko[KK]); \
    if (RDB) {                                                                   \
      _Pragma("unroll") for (int n = 0; n < NF; ++n)                             \
        bfr[KK][n] = *(const bf16x8*)(const void*)((lb_) + (wn*(16*NF) + n*16 + llo)*64 + ko[KK]); \
    }                                                                            \
    STG;                                                                         \
    __builtin_amdgcn_s_barrier();                                                \
    __builtin_amdgcn_s_setprio(1);                                               \
    _Pragma("unroll") for (int m = 0; m < 4; ++m)                                \
      _Pragma("unroll") for (int n = 0; n < NF; ++n)                             \
        acc[MH*4+m][n] = __builtin_amdgcn_mfma_f32_16x16x32_bf16(af[m], bfr[KK][n], acc[MH*4+m][n], 0, 0, 0); \
    __builtin_amdgcn_s_setprio(0);                                               \
    WC;                                                                          \
    __builtin_amdgcn_s_barrier();                                                \
  }

  // prologue: tile0 full -> buf0; tile1 {A0,A2,B0,B1} -> buf1
  SGA(0, 0, 0); SGA(0, 0, 2); SGB(0, 0, 0); SGB(0, 0, 1);
  if (BCH == 4) { SGB(0, 0, 2); SGB(0, 0, 3); }
  SGA(0, 0, 1); SGA(0, 0, 3);
  SGA(1, 1, 0); SGA(1, 1, 2); SGB(1, 1, 0); SGB(1, 1, 1);
  asm volatile("s_waitcnt vmcnt(4)" ::: "memory");
  __builtin_amdgcn_s_barrier();

  const u16* la0 = lds;            const u16* lb0 = lds + ASZ;
  const u16* la1 = lds + BUFS;     const u16* lb1 = la1 + ASZ;

  for (int u = 0; u < NT; u += 2) {
    const int v = u + 1;
    // ---- phases 0-3: tile u from buf0 ----
    PHASE(la0, lb0, 0, 0, true,
          ({ if (BCH == 4) { SGB(v, 1, 2); SGB(v, 1, 3); } else { SGA(v, 1, 1); SGA(v, 1, 3); } }),
          ((void)0));
    PHASE(la0, lb0, 0, 1, true,
          ({ if (BCH == 4) { SGA(v, 1, 1); SGA(v, 1, 3); } }),
          ((void)0));
    PHASE(la0, lb0, 1, 0, false,
          ({ if (u + 2 < NT) { SGA(u + 2, 0, 0); SGA(u + 2, 0, 2); } }),
          ((void)0));
    PHASE(la0, lb0, 1, 1, false,
          ({ if (u + 2 < NT) { SGB(u + 2, 0, 0); SGB(u + 2, 0, 1); } }),
          ({ if (u + 2 < NT) asm volatile("s_waitcnt vmcnt(4)" ::: "memory");
             else            asm volatile("s_waitcnt vmcnt(0)" ::: "memory"); }));
    // ---- phases 4-7: tile v from buf1 ----
    PHASE(la1, lb1, 0, 0, true,
          ({ if (u + 2 < NT) { if (BCH == 4) { SGB(u + 2, 0, 2); SGB(u + 2, 0, 3); }
                               else          { SGA(u + 2, 0, 1); SGA(u + 2, 0, 3); } } }),
          ((void)0));
    PHASE(la1, lb1, 0, 1, true,
          ({ if (u + 2 < NT && BCH == 4) { SGA(u + 2, 0, 1); SGA(u + 2, 0, 3); } }),
          ((void)0));
    PHASE(la1, lb1, 1, 0, false,
          ({ if (v + 2 < NT) { SGA(v + 2, 1, 0); SGA(v + 2, 1, 2); } }),
          ((void)0));
    PHASE(la1, lb1, 1, 1, false,
          ({ if (v + 2 < NT) { SGB(v + 2, 1, 0); SGB(v + 2, 1, 1); } }),
          ({ if (v + 2 < NT) asm volatile("s_waitcnt vmcnt(4)" ::: "memory");
             else            asm volatile("s_waitcnt vmcnt(0)" ::: "memory"); }));
  }
#undef PHASE
#undef SGA
#undef SGB

  // epilogue: C mapping col = n*16+llo, row = 16*frag + lhi*4 + r
#pragma unroll
  for (int am = 0; am < 8; ++am) {
    const int mh = am >> 2, m = am & 3;
    const int rowb = (int)bm0 + wm * 128 + mh * 64 + m * 16 + lhi * 4;
#pragma unroll
    for (int n = 0; n < NF; ++n) {
      const int col = (int)bn0 + wn * (16 * NF) + n * 16 + llo;
#pragma unroll
      for (int r = 0; r < 4; ++r) {
        float v = acc[am][n][r];
        size_t idx = (size_t)(rowb + r) * N + col;
        if (EPI == 0) {
          ((u16*)outp)[idx] = f2bf(v);
        } else if (EPI == 1) {
          float xb = v + bias[col];
          float sp = (xb > 20.f) ? xb : log1pf(__expf(xb));  // softplus
          ((u16*)outp)[idx] = f2bf(sp);
        } else {
          ((float*)outp)[idx] = v;
        }
      }
    }
  }
}

// ---------------- causal depthwise conv (K=4) + SiLU ----------------
__global__ void conv_silu(const u16* __restrict__ xz, const float* __restrict__ w,
                          const float* __restrict__ cb, u16* __restrict__ xs, int total) {
  int idx = blockIdx.x * 256 + threadIdx.x;
  if (idx >= total) return;
  int d = idx & (DINNER - 1);
  int l = (idx >> 11) & (SEQLEN - 1);
  int b = idx >> 22;
  float4 wv = ((const float4*)w)[d];
  float acc = cb[d];
#pragma unroll
  for (int k = 0; k < 4; ++k) {
    int li = l - 3 + k;
    if (li >= 0) {
      float xv = bf2f(xz[(size_t)(b * SEQLEN + li) * (2 * DINNER) + d]);
      acc = fmaf((&wv.x)[k], xv, acc);
    }
  }
  float s = acc / (1.f + __expf(-acc));   // silu
  xs[(size_t)idx] = f2bf(s);
}

// ---------------- x-projection: xproj(ROWS x 32) = xs(ROWS x 2048) @ Wx(2048 x 32) ----------------
__global__ void xproj_kernel(const u16* __restrict__ xs, const float* __restrict__ Wx,
                             float* __restrict__ outp) {
  __shared__ float part[256];
  int row = blockIdx.x;
  int tid = threadIdx.x;
  int c = tid & 31, kp = tid >> 5;
  const u16* xr = xs + (size_t)row * DINNER + kp * 256;
  const float* wp = Wx + (size_t)(kp * 256) * 32 + c;
  float acc = 0.f;
#pragma unroll 4
  for (int kk = 0; kk < 32; ++kk) {
    u16x8 xv = *(const u16x8*)(const void*)(xr + kk * 8);
#pragma unroll
    for (int j = 0; j < 8; ++j)
      acc = fmaf(bf2f(xv[j]), wp[(kk * 8 + j) * 32], acc);
  }
  part[tid] = acc;
  __syncthreads();
  if (tid < 32) {
    float s = 0.f;
#pragma unroll
    for (int p = 0; p < 8; ++p) s += part[p * 32 + tid];
    outp[(size_t)row * 32 + tid] = s;
  }
}

// ---------------- chunked selective scan (delta in bf16) ----------------
#define SC_NC 32                // chunks
#define SC_CL (SEQLEN / SC_NC)  // 64 steps per chunk
#define SC_DG 16                // d-channels per block

__launch_bounds__(512, 2)
__global__ void scan_chunked(const u16* __restrict__ delta, const u16* __restrict__ xs,
                             const float* __restrict__ xproj, const u16* __restrict__ xz,
                             const float* __restrict__ A_log, const float* __restrict__ Dp,
                             u16* __restrict__ yg) {
  __shared__ float cP[SC_NC][SC_DG][DSTATE];   // 32 KB (later reused as h_begin)
  __shared__ float cH[SC_NC][SC_DG][DSTATE];   // 32 KB
  const int tid = threadIdx.x;
  const int dl = tid & 15, ck = tid >> 4;
  const int b = blockIdx.x >> 7, dblk = blockIdx.x & 127;
  const int d = dblk * SC_DG + dl;
  const int r0 = b * SEQLEN + ck * SC_CL;

  float A[DSTATE];
  {
    const f32x4* ap = (const f32x4*)(A_log + (size_t)d * DSTATE);
#pragma unroll
    for (int q = 0; q < 4; ++q) {
      f32x4 a = ap[q];
#pragma unroll
      for (int j = 0; j < 4; ++j) A[q * 4 + j] = -__expf(a[j]);
    }
  }

  // ---- pass 1: local scan, accumulate carry (P, H) ----
  float P[DSTATE], Hh[DSTATE];
#pragma unroll
  for (int s = 0; s < DSTATE; ++s) { P[s] = 1.f; Hh[s] = 0.f; }
#pragma unroll 2
  for (int l = 0; l < SC_CL; ++l) {
    size_t row = (size_t)(r0 + l);
    float dt = bf2f(delta[row * DINNER + d]);
    float xv = bf2f(xs[row * DINNER + d]);
    float dtx = dt * xv;
    const f32x4* bp = (const f32x4*)(xproj + row * 32);
    f32x4 Bq[4];
#pragma unroll
    for (int q = 0; q < 4; ++q) Bq[q] = bp[q];
#pragma unroll
    for (int s = 0; s < DSTATE; ++s) {
      float dA = fmaf(A[s], dt, 1.f);
      P[s] *= dA;
      Hh[s] = fmaf(Hh[s], dA, Bq[s >> 2][s & 3] * dtx);
    }
  }
#pragma unroll
  for (int s = 0; s < DSTATE; ++s) { cP[ck][dl][s] = P[s]; cH[ck][dl][s] = Hh[s]; }
  __syncthreads();

  // ---- pass 2: serial carry composition over 32 chunks ----
  if (tid < SC_DG * DSTATE) {
    int s2 = tid & 15, dd = tid >> 4;
    float h = 0.f;
    for (int c = 0; c < SC_NC; ++c) {
      float p = cP[c][dd][s2], hh = cH[c][dd][s2];
      cP[c][dd][s2] = h;
      h = fmaf(p, h, hh);
    }
  }
  __syncthreads();

  // ---- pass 3: re-scan from h_begin, emit gated output ----
  float h[DSTATE];
#pragma unroll
  for (int s = 0; s < DSTATE; ++s) h[s] = cP[ck][dl][s];
  const float Dv = Dp[d];
#pragma unroll 2
  for (int l = 0; l < SC_CL; ++l) {
    size_t row = (size_t)(r0 + l);
    float dt = bf2f(delta[row * DINNER + d]);
    float xv = bf2f(xs[row * DINNER + d]);
    float dtx = dt * xv;
    const f32x4* bp = (const f32x4*)(xproj + row * 32);
    f32x4 Bq[4], Cq[4];
#pragma unroll
    for (int q = 0; q < 4; ++q) { Bq[q] = bp[q]; Cq[q] = bp[q + 4]; }
    float yp = 0.f;
#pragma unroll
    for (int s = 0; s < DSTATE; ++s) {
      float dA = fmaf(A[s], dt, 1.f);
      h[s] = fmaf(h[s], dA, Bq[s >> 2][s & 3] * dtx);
      yp = fmaf(h[s], Cq[s >> 2][s & 3], yp);
    }
    float z = bf2f(xz[row * (2 * DINNER) + DINNER + d]);
    float y = yp + Dv * xv;
    float g = z / (1.f + __expf(-z));
    yg[row * DINNER + d] = f2bf(y * g);
  }
}

extern "C" void kernel_launch(void* const* d_in, const int* in_sizes, int n_in,
                              void* d_out, int out_size, void* d_ws, size_t ws_size,
                              hipStream_t stream) {
  const float* x       = (const float*)d_in[0];
  const float* W_in    = (const float*)d_in[1];
  const float* conv_w  = (const float*)d_in[2];
  const float* conv_b  = (const float*)d_in[3];
  const float* W_xproj = (const float*)d_in[4];
  const float* W_dt    = (const float*)d_in[5];
  const float* b_dt    = (const float*)d_in[6];
  const float* A_log   = (const float*)d_in[7];
  const float* D_param = (const float*)d_in[8];
  const float* W_out   = (const float*)d_in[9];
  float* out = (float*)d_out;

  char* ws = (char*)d_ws;
  const size_t MB = 1ull << 20;
  u16*   x_bf  = (u16*)(ws);              // 16 MB   [dead after GEMM1]
  u16*   WinT  = (u16*)(ws + 16 * MB);    //  8 MB   [dead after GEMM1]
  u16*   WdtT  = (u16*)(ws + 24 * MB);    //  8 MB   [dead after GEMM2]
  u16*   xz_bf = (u16*)(ws + 32 * MB);    // 64 MB   [live through scan]
  u16*   xs_bf = (u16*)(ws + 96 * MB);    // 32 MB   [live through scan]
  u16*   delta = (u16*)(ws + 128 * MB);   // 32 MB (bf16 now)
  float* xpj   = (float*)(ws + 192 * MB); //  1 MB
  u16*   WoutT = (u16*)(ws + 193 * MB);   //  4 MB
  u16*   yg    = (u16*)(ws);              // 32 MB, aliases x_bf/WinT (dead by then)

  hipFuncSetAttribute((const void*)gemm8p<0, 256>, hipFuncAttributeMaxDynamicSharedMemorySize, 131072);
  hipFuncSetAttribute((const void*)gemm8p<1, 256>, hipFuncAttributeMaxDynamicSharedMemorySize, 131072);
  hipFuncSetAttribute((const void*)gemm8p<2, 128>, hipFuncAttributeMaxDynamicSharedMemorySize, 98304);

  dim3 tb(32, 8);

  // 1) casts / weight transposes
  cast_f32_bf16<<<(ROWS * DMODEL / 4 + 255) / 256, 256, 0, stream>>>(x, x_bf, ROWS * DMODEL / 4);
  transpose_cast<<<dim3((2 * DINNER) / 32, DMODEL / 32), tb, 0, stream>>>(W_in, WinT, DMODEL, 2 * DINNER);
  transpose_cast<<<dim3(DINNER / 32, DINNER / 32), tb, 0, stream>>>(W_dt, WdtT, DINNER, DINNER);
  transpose_cast<<<dim3(DMODEL / 32, DINNER / 32), tb, 0, stream>>>(W_out, WoutT, DINNER, DMODEL);

  // 2) xz = x @ W_in   (8192 x 4096, K=1024) -> bf16. grid 512, XCD tile 8x8
  gemm8p<0, 256><<<512, 512, 131072, stream>>>(x_bf, WinT, xz_bf, nullptr,
                                               ROWS, 2 * DINNER, DMODEL, 16, 8, 8);

  // 3) xs = silu(causal_conv(xc) + conv_b) -> bf16
  conv_silu<<<(ROWS * DINNER) / 256, 256, 0, stream>>>(xz_bf, conv_w, conv_b, xs_bf, ROWS * DINNER);

  // 4) delta = softplus(xs @ W_dt + b_dt) (8192 x 2048, K=2048) -> bf16. grid 256, XCD tile 4x8
  gemm8p<1, 256><<<256, 512, 131072, stream>>>(xs_bf, WdtT, delta, b_dt,
                                               ROWS, DINNER, DINNER, 8, 4, 8);

  // 5) [Bs|Cs] = xs @ W_xproj   (8192 x 32) -> f32
  xproj_kernel<<<ROWS, 256, 0, stream>>>(xs_bf, W_xproj, xpj);

  // 6) chunked selective scan + D-skip + silu(z) gate -> yg bf16
  scan_chunked<<<BATCH * (DINNER / SC_DG), 512, 0, stream>>>(
      delta, xs_bf, xpj, xz_bf, A_log, D_param, yg);

  // 7) out = yg @ W_out  (8192 x 1024, K=2048) -> f32. BN=128, grid 256, XCD tile 4x8
  gemm8p<2, 128><<<256, 512, 98304, stream>>>(yg, WoutT, out, nullptr,
                                              ROWS, DMODEL, DINNER, 8, 4, 8);
}

// Round 5
// 476.479 us; speedup vs baseline: 4.2665x; 1.0767x over previous
//
#include <hip/hip_runtime.h>

#define AS1 __attribute__((address_space(1)))
#define AS3 __attribute__((address_space(3)))

typedef unsigned short u16;
typedef unsigned int u32;
typedef __attribute__((ext_vector_type(8))) __bf16 bf16x8;
typedef __attribute__((ext_vector_type(8))) unsigned short u16x8;
typedef __attribute__((ext_vector_type(4))) float f32x4;

// Problem constants
#define BATCH   4
#define SEQLEN  2048
#define DMODEL  1024
#define DINNER  2048
#define DSTATE  16
#define ROWS    (BATCH * SEQLEN)   // 8192

__device__ __forceinline__ u16 f2bf(float f) {
  union { float f; unsigned u; } v; v.f = f;
  unsigned u = v.u;
  return (u16)((u + 0x7fffu + ((u >> 16) & 1u)) >> 16);   // RNE
}
__device__ __forceinline__ float bf2f(u16 s) {
  union { unsigned u; float f; } v; v.u = ((unsigned)s) << 16;
  return v.f;
}
__device__ __forceinline__ float bflo(u32 p) { union { unsigned u; float f; } v; v.u = p << 16; return v.f; }
__device__ __forceinline__ float bfhi(u32 p) { union { unsigned u; float f; } v; v.u = p & 0xffff0000u; return v.f; }

// ---------------- cast f32 -> bf16 (4 elems/thread) ----------------
__global__ void cast_f32_bf16(const float* __restrict__ in, u16* __restrict__ out, int n4) {
  int i = blockIdx.x * blockDim.x + threadIdx.x;
  if (i >= n4) return;
  float4 v = ((const float4*)in)[i];
  ushort4 o;
  o.x = f2bf(v.x); o.y = f2bf(v.y); o.z = f2bf(v.z); o.w = f2bf(v.w);
  ((ushort4*)out)[i] = o;
}

// ---------------- transpose + cast: in f32 (R x C) -> out bf16 (C x R) ----------------
__global__ void transpose_cast(const float* __restrict__ in, u16* __restrict__ out, int R, int C) {
  __shared__ float tile[32][33];
  int x  = blockIdx.x * 32 + threadIdx.x;
  int y0 = blockIdx.y * 32;
#pragma unroll
  for (int j = 0; j < 32; j += 8)
    tile[threadIdx.y + j][threadIdx.x] = in[(size_t)(y0 + threadIdx.y + j) * C + x];
  __syncthreads();
  int xo  = blockIdx.y * 32 + threadIdx.x;
  int yo0 = blockIdx.x * 32;
#pragma unroll
  for (int j = 0; j < 32; j += 8)
    out[(size_t)(yo0 + threadIdx.y + j) * R + xo] = f2bf(tile[threadIdx.x][threadIdx.y + j]);
}

// ---------------- 256xBN 8-phase bf16 MFMA GEMM: C = A(MxK) * Bt(NxK)^T ----------------
// (unchanged from R4 — fine-interleaved phases, counted vmcnt, T2 swizzle, 2D XCD tiles)
template<int EPI, int BN_>
__launch_bounds__(512, 1)
__global__ void gemm8p(const u16* __restrict__ A, const u16* __restrict__ Bt,
                       void* __restrict__ outp, const float* __restrict__ bias,
                       int M, int N, int K, int gn, int rr, int cc) {
  constexpr int NF   = BN_ / 64;
  constexpr int BCH  = BN_ / 64;
  constexpr int ASZ  = 256 * 64;
  constexpr int BSZ  = BN_ * 64;
  constexpr int BUFS = ASZ + BSZ;
  extern __shared__ u16 lds[];

  const int xcd = blockIdx.x & 7, kb = blockIdx.x >> 3;
  const int tpr = gn / cc;
  const int bm  = (xcd / tpr) * rr + kb / cc;
  const int bn  = (xcd % tpr) * cc + kb % cc;

  const int tid  = threadIdx.x;
  const int wave = tid >> 6, lane = tid & 63;
  const int wm = wave >> 2, wn = wave & 3;
  const int llo = lane & 15, lhi = lane >> 4;
  const size_t bm0 = (size_t)bm * 256, bn0 = (size_t)bn * BN_;
  const int NT = K >> 6;

  const u16* gA[4];
#pragma unroll
  for (int ch = 0; ch < 4; ++ch) {
    int row  = ch * 64 + (tid >> 3);
    int scol = ((tid & 7) ^ (row & 7)) << 3;
    gA[ch] = A + (bm0 + row) * (size_t)K + scol;
  }
  const u16* gB[BCH];
#pragma unroll
  for (int ch = 0; ch < BCH; ++ch) {
    int row  = ch * 64 + (tid >> 3);
    int scol = ((tid & 7) ^ (row & 7)) << 3;
    gB[ch] = Bt + (bn0 + row) * (size_t)K + scol;
  }

  const int mask = (llo & 7) << 4;
  const int ko[2] = { ((0 + lhi * 16) ^ mask) >> 1, ((64 + lhi * 16) ^ mask) >> 1 };

#define SGA(t, bsel, ch) __builtin_amdgcn_global_load_lds(                       \
    (const AS1 void*)(gA[ch] + ((size_t)(t) << 6)),                              \
    (AS3 void*)(lds + (bsel) * BUFS + (ch) * 4096 + wave * 512), 16, 0, 0)
#define SGB(t, bsel, ch) __builtin_amdgcn_global_load_lds(                       \
    (const AS1 void*)(gB[ch] + ((size_t)(t) << 6)),                              \
    (AS3 void*)(lds + (bsel) * BUFS + ASZ + (ch) * 4096 + wave * 512), 16, 0, 0)

  f32x4 acc[8][NF] = {};
  bf16x8 bfr[2][NF];

#define PHASE(la_, lb_, MH, KK, RDB, STG, WC)                                    \
  {                                                                              \
    bf16x8 af[4];                                                                \
    _Pragma("unroll") for (int m = 0; m < 4; ++m)                                \
      af[m] = *(const bf16x8*)(const void*)((la_) + (wm*128 + MH*64 + m*16 + llo)*64 + ko[KK]); \
    if (RDB) {                                                                   \
      _Pragma("unroll") for (int n = 0; n < NF; ++n)                             \
        bfr[KK][n] = *(const bf16x8*)(const void*)((lb_) + (wn*(16*NF) + n*16 + llo)*64 + ko[KK]); \
    }                                                                            \
    STG;                                                                         \
    __builtin_amdgcn_s_barrier();                                                \
    __builtin_amdgcn_s_setprio(1);                                               \
    _Pragma("unroll") for (int m = 0; m < 4; ++m)                                \
      _Pragma("unroll") for (int n = 0; n < NF; ++n)                             \
        acc[MH*4+m][n] = __builtin_amdgcn_mfma_f32_16x16x32_bf16(af[m], bfr[KK][n], acc[MH*4+m][n], 0, 0, 0); \
    __builtin_amdgcn_s_setprio(0);                                               \
    WC;                                                                          \
    __builtin_amdgcn_s_barrier();                                                \
  }

  SGA(0, 0, 0); SGA(0, 0, 2); SGB(0, 0, 0); SGB(0, 0, 1);
  if (BCH == 4) { SGB(0, 0, 2); SGB(0, 0, 3); }
  SGA(0, 0, 1); SGA(0, 0, 3);
  SGA(1, 1, 0); SGA(1, 1, 2); SGB(1, 1, 0); SGB(1, 1, 1);
  asm volatile("s_waitcnt vmcnt(4)" ::: "memory");
  __builtin_amdgcn_s_barrier();

  const u16* la0 = lds;            const u16* lb0 = lds + ASZ;
  const u16* la1 = lds + BUFS;     const u16* lb1 = la1 + ASZ;

  for (int u = 0; u < NT; u += 2) {
    const int v = u + 1;
    PHASE(la0, lb0, 0, 0, true,
          ({ if (BCH == 4) { SGB(v, 1, 2); SGB(v, 1, 3); } else { SGA(v, 1, 1); SGA(v, 1, 3); } }),
          ((void)0));
    PHASE(la0, lb0, 0, 1, true,
          ({ if (BCH == 4) { SGA(v, 1, 1); SGA(v, 1, 3); } }),
          ((void)0));
    PHASE(la0, lb0, 1, 0, false,
          ({ if (u + 2 < NT) { SGA(u + 2, 0, 0); SGA(u + 2, 0, 2); } }),
          ((void)0));
    PHASE(la0, lb0, 1, 1, false,
          ({ if (u + 2 < NT) { SGB(u + 2, 0, 0); SGB(u + 2, 0, 1); } }),
          ({ if (u + 2 < NT) asm volatile("s_waitcnt vmcnt(4)" ::: "memory");
             else            asm volatile("s_waitcnt vmcnt(0)" ::: "memory"); }));
    PHASE(la1, lb1, 0, 0, true,
          ({ if (u + 2 < NT) { if (BCH == 4) { SGB(u + 2, 0, 2); SGB(u + 2, 0, 3); }
                               else          { SGA(u + 2, 0, 1); SGA(u + 2, 0, 3); } } }),
          ((void)0));
    PHASE(la1, lb1, 0, 1, true,
          ({ if (u + 2 < NT && BCH == 4) { SGA(u + 2, 0, 1); SGA(u + 2, 0, 3); } }),
          ((void)0));
    PHASE(la1, lb1, 1, 0, false,
          ({ if (v + 2 < NT) { SGA(v + 2, 1, 0); SGA(v + 2, 1, 2); } }),
          ((void)0));
    PHASE(la1, lb1, 1, 1, false,
          ({ if (v + 2 < NT) { SGB(v + 2, 1, 0); SGB(v + 2, 1, 1); } }),
          ({ if (v + 2 < NT) asm volatile("s_waitcnt vmcnt(4)" ::: "memory");
             else            asm volatile("s_waitcnt vmcnt(0)" ::: "memory"); }));
  }
#undef PHASE
#undef SGA
#undef SGB

#pragma unroll
  for (int am = 0; am < 8; ++am) {
    const int mh = am >> 2, m = am & 3;
    const int rowb = (int)bm0 + wm * 128 + mh * 64 + m * 16 + lhi * 4;
#pragma unroll
    for (int n = 0; n < NF; ++n) {
      const int col = (int)bn0 + wn * (16 * NF) + n * 16 + llo;
#pragma unroll
      for (int r = 0; r < 4; ++r) {
        float v = acc[am][n][r];
        size_t idx = (size_t)(rowb + r) * N + col;
        if (EPI == 0) {
          ((u16*)outp)[idx] = f2bf(v);
        } else if (EPI == 1) {
          float xb = v + bias[col];
          float sp = (xb > 20.f) ? xb : log1pf(__expf(xb));  // softplus
          ((u16*)outp)[idx] = f2bf(sp);
        } else {
          ((float*)outp)[idx] = v;
        }
      }
    }
  }
}

// ---------------- causal depthwise conv (K=4) + SiLU, 4 d per thread ----------------
__global__ void conv_silu4(const u16* __restrict__ xz, const float* __restrict__ w,
                           const float* __restrict__ cb, u16* __restrict__ xs, int total4) {
  int idx = blockIdx.x * 256 + threadIdx.x;
  if (idx >= total4) return;
  int d4 = idx & (DINNER / 4 - 1);           // 512 groups of 4 d
  int l  = (idx >> 9) & (SEQLEN - 1);
  int b  = idx >> 20;
  int d  = d4 * 4;
  float4 wv[4];
#pragma unroll
  for (int j = 0; j < 4; ++j) wv[j] = ((const float4*)w)[d + j];
  float4 bias = *(const float4*)(cb + d);
  float acc[4] = { bias.x, bias.y, bias.z, bias.w };
#pragma unroll
  for (int k = 0; k < 4; ++k) {
    int li = l - 3 + k;
    if (li >= 0) {
      ushort4 xv = *(const ushort4*)(xz + (size_t)(b * SEQLEN + li) * (2 * DINNER) + d);
      acc[0] = fmaf((&wv[0].x)[k], bf2f(xv.x), acc[0]);
      acc[1] = fmaf((&wv[1].x)[k], bf2f(xv.y), acc[1]);
      acc[2] = fmaf((&wv[2].x)[k], bf2f(xv.z), acc[2]);
      acc[3] = fmaf((&wv[3].x)[k], bf2f(xv.w), acc[3]);
    }
  }
  ushort4 o;
  o.x = f2bf(acc[0] / (1.f + __expf(-acc[0])));
  o.y = f2bf(acc[1] / (1.f + __expf(-acc[1])));
  o.z = f2bf(acc[2] / (1.f + __expf(-acc[2])));
  o.w = f2bf(acc[3] / (1.f + __expf(-acc[3])));
  *(ushort4*)(xs + (size_t)idx * 4) = o;
}

// ---------------- x-projection: xproj(ROWS x 32) = xs(ROWS x 2048) @ Wx(2048 x 32) ----------------
__global__ void xproj_kernel(const u16* __restrict__ xs, const float* __restrict__ Wx,
                             float* __restrict__ outp) {
  __shared__ float part[256];
  int row = blockIdx.x;
  int tid = threadIdx.x;
  int c = tid & 31, kp = tid >> 5;
  const u16* xr = xs + (size_t)row * DINNER + kp * 256;
  const float* wp = Wx + (size_t)(kp * 256) * 32 + c;
  float acc = 0.f;
#pragma unroll 4
  for (int kk = 0; kk < 32; ++kk) {
    u16x8 xv = *(const u16x8*)(const void*)(xr + kk * 8);
#pragma unroll
    for (int j = 0; j < 8; ++j)
      acc = fmaf(bf2f(xv[j]), wp[(kk * 8 + j) * 32], acc);
  }
  part[tid] = acc;
  __syncthreads();
  if (tid < 32) {
    float s = 0.f;
#pragma unroll
    for (int p = 0; p < 8; ++p) s += part[p * 32 + tid];
    outp[(size_t)row * 32 + tid] = s;
  }
}

// ---------------- chunked selective scan v3 ----------------
// Block = (batch b, 32 d). 512 threads = 16 d-lanes (x2 d each) x 32 chunks of 64.
// Coalescing: 16 lanes x 4 B (bf16 pair) = 64 B segments on delta/xs/z/yg.
// Depth-2 pipeline on HBM streams, depth-1 on xproj (L2 broadcast).
// Carries in 132 KB dynamic LDS, stride 33 (bank-conflict-free).
#define SC_NC 32                // chunks
#define SC_CL 64                // steps per chunk
#define SC_LDS (2 * SC_NC * 16 * 33 * 4)   // 135168 B

__launch_bounds__(512, 1)
__global__ void scan_v3(const u16* __restrict__ delta, const u16* __restrict__ xs,
                        const float* __restrict__ xproj, const u16* __restrict__ xz,
                        const float* __restrict__ A_log, const float* __restrict__ Dp,
                        u16* __restrict__ yg) {
  extern __shared__ float smem[];
  float* cP = smem;                        // [ck][dl][33]  (P then h_begin)
  float* cH = smem + SC_NC * 16 * 33;      // [ck][dl][33]
  const int tid = threadIdx.x;
  const int dl = tid & 15, ck = tid >> 4;
  const int b = blockIdx.x >> 6, dblk = blockIdx.x & 63;
  const int d0 = dblk * 32 + dl * 2;       // thread owns d0, d0+1
  const int r0 = b * SEQLEN + ck * SC_CL;

  float A0[DSTATE], A1[DSTATE];
  {
    const f32x4* ap0 = (const f32x4*)(A_log + (size_t)d0 * DSTATE);
    const f32x4* ap1 = (const f32x4*)(A_log + (size_t)(d0 + 1) * DSTATE);
#pragma unroll
    for (int q = 0; q < 4; ++q) {
      f32x4 a0 = ap0[q], a1 = ap1[q];
#pragma unroll
      for (int j = 0; j < 4; ++j) { A0[q * 4 + j] = -__expf(a0[j]); A1[q * 4 + j] = -__expf(a1[j]); }
    }
  }

  const u32* dP = (const u32*)(delta + (size_t)r0 * DINNER + d0);
  const u32* xP = (const u32*)(xs    + (size_t)r0 * DINNER + d0);
  const u32* zP = (const u32*)(xz + (size_t)r0 * (2 * DINNER) + DINNER + d0);
  const float* bP = xproj + (size_t)r0 * 32;
  const int DW = DINNER / 2;               // u32 stride per row
  const int ZW = DINNER;                   // u32 stride per xz row

  // ---- pass 1: local scan, accumulate carry (P, H) ----
  float P0[DSTATE], P1[DSTATE], H0[DSTATE], H1[DSTATE];
#pragma unroll
  for (int s = 0; s < DSTATE; ++s) { P0[s] = P1[s] = 1.f; H0[s] = H1[s] = 0.f; }
  {
    u32 dq0 = dP[0], xq0 = xP[0];
    u32 dq1 = dP[DW], xq1 = xP[DW];
    f32x4 Bn[4];
#pragma unroll
    for (int q = 0; q < 4; ++q) Bn[q] = ((const f32x4*)bP)[q];
    for (int l = 0; l < SC_CL; ++l) {
      const u32 dc = dq0, xc = xq0;
      dq0 = dq1; xq0 = xq1;
      if (l + 2 < SC_CL) { dq1 = dP[(l + 2) * DW]; xq1 = xP[(l + 2) * DW]; }
      f32x4 Bc[4] = { Bn[0], Bn[1], Bn[2], Bn[3] };
      if (l + 1 < SC_CL) {
        const f32x4* bn = (const f32x4*)(bP + (l + 1) * 32);
#pragma unroll
        for (int q = 0; q < 4; ++q) Bn[q] = bn[q];
      }
      float dt0 = bflo(dc), dt1 = bfhi(dc);
      float x0 = bflo(xc),  x1 = bfhi(xc);
      float dtx0 = dt0 * x0, dtx1 = dt1 * x1;
#pragma unroll
      for (int s = 0; s < DSTATE; ++s) {
        float bs = Bc[s >> 2][s & 3];
        float dA0 = fmaf(A0[s], dt0, 1.f);
        float dA1 = fmaf(A1[s], dt1, 1.f);
        P0[s] *= dA0; P1[s] *= dA1;
        H0[s] = fmaf(H0[s], dA0, bs * dtx0);
        H1[s] = fmaf(H1[s], dA1, bs * dtx1);
      }
    }
  }
  {
    float* p = cP + (ck * 16 + dl) * 33;
    float* h = cH + (ck * 16 + dl) * 33;
#pragma unroll
    for (int s = 0; s < DSTATE; ++s) {
      p[s] = P0[s]; p[16 + s] = P1[s];
      h[s] = H0[s]; h[16 + s] = H1[s];
    }
  }
  __syncthreads();

  // ---- pass 2: serial carry composition over 32 chunks (all 512 threads) ----
  {
    const int s2 = tid & 15, dd = tid >> 4;          // dd in [0,32)
    const int idx = (dd & 1) * 16 + s2;
    float* pbase = cP + (dd >> 1) * 33 + idx;
    float* hbase = cH + (dd >> 1) * 33 + idx;
    float h = 0.f;
    for (int c = 0; c < SC_NC; ++c) {
      float p = pbase[c * 16 * 33], hh = hbase[c * 16 * 33];
      pbase[c * 16 * 33] = h;                        // h_begin for chunk c
      h = fmaf(p, h, hh);
    }
  }
  __syncthreads();

  // ---- pass 3: re-scan from h_begin, emit gated output ----
  float h0[DSTATE], h1[DSTATE];
  {
    const float* p = cP + (ck * 16 + dl) * 33;
#pragma unroll
    for (int s = 0; s < DSTATE; ++s) { h0[s] = p[s]; h1[s] = p[16 + s]; }
  }
  const float Dv0 = Dp[d0], Dv1 = Dp[d0 + 1];
  u32* yP = (u32*)(yg + (size_t)r0 * DINNER + d0);
  {
    u32 dq0 = dP[0], xq0 = xP[0], zq0 = zP[0];
    u32 dq1 = dP[DW], xq1 = xP[DW], zq1 = zP[ZW];
    f32x4 Bn[4], Cn[4];
#pragma unroll
    for (int q = 0; q < 4; ++q) { Bn[q] = ((const f32x4*)bP)[q]; Cn[q] = ((const f32x4*)bP)[q + 4]; }
    for (int l = 0; l < SC_CL; ++l) {
      const u32 dc = dq0, xc = xq0, zc = zq0;
      dq0 = dq1; xq0 = xq1; zq0 = zq1;
      if (l + 2 < SC_CL) { dq1 = dP[(l + 2) * DW]; xq1 = xP[(l + 2) * DW]; zq1 = zP[(l + 2) * ZW]; }
      f32x4 Bc[4] = { Bn[0], Bn[1], Bn[2], Bn[3] };
      f32x4 Cc[4] = { Cn[0], Cn[1], Cn[2], Cn[3] };
      if (l + 1 < SC_CL) {
        const f32x4* bn = (const f32x4*)(bP + (l + 1) * 32);
#pragma unroll
        for (int q = 0; q < 4; ++q) { Bn[q] = bn[q]; Cn[q] = bn[q + 4]; }
      }
      float dt0 = bflo(dc), dt1 = bfhi(dc);
      float x0 = bflo(xc),  x1 = bfhi(xc);
      float dtx0 = dt0 * x0, dtx1 = dt1 * x1;
      float yp0 = 0.f, yp1 = 0.f;
#pragma unroll
      for (int s = 0; s < DSTATE; ++s) {
        float bs = Bc[s >> 2][s & 3];
        float cs = Cc[s >> 2][s & 3];
        float dA0 = fmaf(A0[s], dt0, 1.f);
        float dA1 = fmaf(A1[s], dt1, 1.f);
        h0[s] = fmaf(h0[s], dA0, bs * dtx0);
        h1[s] = fmaf(h1[s], dA1, bs * dtx1);
        yp0 = fmaf(h0[s], cs, yp0);
        yp1 = fmaf(h1[s], cs, yp1);
      }
      float z0 = bflo(zc), z1 = bfhi(zc);
      float y0 = (yp0 + Dv0 * x0) * (z0 / (1.f + __expf(-z0)));
      float y1 = (yp1 + Dv1 * x1) * (z1 / (1.f + __expf(-z1)));
      yP[l * DW] = (u32)f2bf(y0) | ((u32)f2bf(y1) << 16);
    }
  }
}

extern "C" void kernel_launch(void* const* d_in, const int* in_sizes, int n_in,
                              void* d_out, int out_size, void* d_ws, size_t ws_size,
                              hipStream_t stream) {
  const float* x       = (const float*)d_in[0];
  const float* W_in    = (const float*)d_in[1];
  const float* conv_w  = (const float*)d_in[2];
  const float* conv_b  = (const float*)d_in[3];
  const float* W_xproj = (const float*)d_in[4];
  const float* W_dt    = (const float*)d_in[5];
  const float* b_dt    = (const float*)d_in[6];
  const float* A_log   = (const float*)d_in[7];
  const float* D_param = (const float*)d_in[8];
  const float* W_out   = (const float*)d_in[9];
  float* out = (float*)d_out;

  char* ws = (char*)d_ws;
  const size_t MB = 1ull << 20;
  u16*   x_bf  = (u16*)(ws);              // 16 MB   [dead after GEMM1]
  u16*   WinT  = (u16*)(ws + 16 * MB);    //  8 MB   [dead after GEMM1]
  u16*   WdtT  = (u16*)(ws + 24 * MB);    //  8 MB   [dead after GEMM2]
  u16*   xz_bf = (u16*)(ws + 32 * MB);    // 64 MB   [live through scan]
  u16*   xs_bf = (u16*)(ws + 96 * MB);    // 32 MB   [live through scan]
  u16*   delta = (u16*)(ws + 128 * MB);   // 32 MB (bf16)
  float* xpj   = (float*)(ws + 192 * MB); //  1 MB
  u16*   WoutT = (u16*)(ws + 193 * MB);   //  4 MB
  u16*   yg    = (u16*)(ws);              // 32 MB, aliases x_bf/WinT/WdtT (dead by then)

  hipFuncSetAttribute((const void*)gemm8p<0, 256>, hipFuncAttributeMaxDynamicSharedMemorySize, 131072);
  hipFuncSetAttribute((const void*)gemm8p<1, 256>, hipFuncAttributeMaxDynamicSharedMemorySize, 131072);
  hipFuncSetAttribute((const void*)gemm8p<2, 128>, hipFuncAttributeMaxDynamicSharedMemorySize, 98304);
  hipFuncSetAttribute((const void*)scan_v3, hipFuncAttributeMaxDynamicSharedMemorySize, SC_LDS);

  dim3 tb(32, 8);

  // 1) casts / weight transposes
  cast_f32_bf16<<<(ROWS * DMODEL / 4 + 255) / 256, 256, 0, stream>>>(x, x_bf, ROWS * DMODEL / 4);
  transpose_cast<<<dim3((2 * DINNER) / 32, DMODEL / 32), tb, 0, stream>>>(W_in, WinT, DMODEL, 2 * DINNER);
  transpose_cast<<<dim3(DINNER / 32, DINNER / 32), tb, 0, stream>>>(W_dt, WdtT, DINNER, DINNER);
  transpose_cast<<<dim3(DMODEL / 32, DINNER / 32), tb, 0, stream>>>(W_out, WoutT, DINNER, DMODEL);

  // 2) xz = x @ W_in   (8192 x 4096, K=1024) -> bf16. grid 512, XCD tile 8x8
  gemm8p<0, 256><<<512, 512, 131072, stream>>>(x_bf, WinT, xz_bf, nullptr,
                                               ROWS, 2 * DINNER, DMODEL, 16, 8, 8);

  // 3) xs = silu(causal_conv(xc) + conv_b) -> bf16 (4 d per thread)
  conv_silu4<<<(ROWS * DINNER / 4) / 256, 256, 0, stream>>>(
      xz_bf, conv_w, conv_b, xs_bf, ROWS * DINNER / 4);

  // 4) delta = softplus(xs @ W_dt + b_dt) (8192 x 2048, K=2048) -> bf16. grid 256, XCD tile 4x8
  gemm8p<1, 256><<<256, 512, 131072, stream>>>(xs_bf, WdtT, delta, b_dt,
                                               ROWS, DINNER, DINNER, 8, 4, 8);

  // 5) [Bs|Cs] = xs @ W_xproj   (8192 x 32) -> f32
  xproj_kernel<<<ROWS, 256, 0, stream>>>(xs_bf, W_xproj, xpj);

  // 6) chunked selective scan v3 + D-skip + silu(z) gate -> yg bf16
  scan_v3<<<BATCH * (DINNER / 32), 512, SC_LDS, stream>>>(
      delta, xs_bf, xpj, xz_bf, A_log, D_param, yg);

  // 7) out = yg @ W_out  (8192 x 1024, K=2048) -> f32. BN=128, grid 256, XCD tile 4x8
  gemm8p<2, 128><<<256, 512, 98304, stream>>>(yg, WoutT, out, nullptr,
                                              ROWS, DMODEL, DINNER, 8, 4, 8);
}

// Round 6
// 471.492 us; speedup vs baseline: 4.3116x; 1.0106x over previous
//
#include <hip/hip_runtime.h>

#define AS1 __attribute__((address_space(1)))
#define AS3 __attribute__((address_space(3)))

typedef unsigned short u16;
typedef unsigned int u32;
typedef __attribute__((ext_vector_type(8))) __bf16 bf16x8;
typedef __attribute__((ext_vector_type(8))) unsigned short u16x8;
typedef __attribute__((ext_vector_type(4))) float f32x4;

// Problem constants
#define BATCH   4
#define SEQLEN  2048
#define DMODEL  1024
#define DINNER  2048
#define DSTATE  16
#define ROWS    (BATCH * SEQLEN)   // 8192

__device__ __forceinline__ u16 f2bf(float f) {
  union { float f; unsigned u; } v; v.f = f;
  unsigned u = v.u;
  return (u16)((u + 0x7fffu + ((u >> 16) & 1u)) >> 16);   // RNE
}
__device__ __forceinline__ float bf2f(u16 s) {
  union { unsigned u; float f; } v; v.u = ((unsigned)s) << 16;
  return v.f;
}
__device__ __forceinline__ float bflo(u32 p) { union { unsigned u; float f; } v; v.u = p << 16; return v.f; }
__device__ __forceinline__ float bfhi(u32 p) { union { unsigned u; float f; } v; v.u = p & 0xffff0000u; return v.f; }

// asm ds_read_b128 with compile-time offset; address is a 32-bit LDS byte address.
template<int IMM>
__device__ __forceinline__ bf16x8 dsr(unsigned addr) {
  bf16x8 r;
  asm volatile("ds_read_b128 %0, %1 offset:%2" : "=&v"(r) : "v"(addr), "i"(IMM));
  return r;
}
__device__ __forceinline__ unsigned lds_addr(const u16* p) {
  return (unsigned)(size_t)(const AS3 u16*)p;
}

// ---------------- cast f32 -> bf16 (4 elems/thread) ----------------
__global__ void cast_f32_bf16(const float* __restrict__ in, u16* __restrict__ out, int n4) {
  int i = blockIdx.x * blockDim.x + threadIdx.x;
  if (i >= n4) return;
  float4 v = ((const float4*)in)[i];
  ushort4 o;
  o.x = f2bf(v.x); o.y = f2bf(v.y); o.z = f2bf(v.z); o.w = f2bf(v.w);
  ((ushort4*)out)[i] = o;
}

// ---------------- transpose + cast: in f32 (R x C) -> out bf16 (C x R) ----------------
__global__ void transpose_cast(const float* __restrict__ in, u16* __restrict__ out, int R, int C) {
  __shared__ float tile[32][33];
  int x  = blockIdx.x * 32 + threadIdx.x;
  int y0 = blockIdx.y * 32;
#pragma unroll
  for (int j = 0; j < 32; j += 8)
    tile[threadIdx.y + j][threadIdx.x] = in[(size_t)(y0 + threadIdx.y + j) * C + x];
  __syncthreads();
  int xo  = blockIdx.y * 32 + threadIdx.x;
  int yo0 = blockIdx.x * 32;
#pragma unroll
  for (int j = 0; j < 32; j += 8)
    out[(size_t)(yo0 + threadIdx.y + j) * R + xo] = f2bf(tile[threadIdx.x][threadIdx.y + j]);
}

// ---------------- 256xBN 8-phase bf16 MFMA GEMM: C = A(MxK) * Bt(NxK)^T ----------------
// All K-loop sync is inline asm (s_barrier / counted vmcnt / lgkmcnt) and all LDS
// reads are asm ds_read_b128 so the compiler's memory legalizer cannot insert
// conservative vmcnt(0) drains (they alias the global_load_lds destinations).
// EPI: 0 = store bf16, 1 = softplus(v + bias[col]) -> bf16, 2 = store f32
template<int EPI, int BN_>
__launch_bounds__(512, 1)
__global__ void gemm8p(const u16* __restrict__ A, const u16* __restrict__ Bt,
                       void* __restrict__ outp, const float* __restrict__ bias,
                       int M, int N, int K, int gn, int rr, int cc) {
  constexpr int NF   = BN_ / 64;        // n-frags per wave (4 or 2)
  constexpr int BCH  = BN_ / 64;        // B chunks of 64 rows (4 or 2)
  constexpr int ASZ  = 256 * 64;        // u16 per A tile
  constexpr int BSZ  = BN_ * 64;
  constexpr int BUFS = ASZ + BSZ;       // u16 per buffer
  extern __shared__ u16 lds[];

  const int xcd = blockIdx.x & 7, kb = blockIdx.x >> 3;
  const int tpr = gn / cc;
  const int bm  = (xcd / tpr) * rr + kb / cc;
  const int bn  = (xcd % tpr) * cc + kb % cc;

  const int tid  = threadIdx.x;
  const int wave = tid >> 6, lane = tid & 63;
  const int wm = wave >> 2, wn = wave & 3;
  const int llo = lane & 15, lhi = lane >> 4;
  const size_t bm0 = (size_t)bm * 256, bn0 = (size_t)bn * BN_;
  const int NT = K >> 6;

  // staging source pointers (pre-swizzled column slot so LDS stays linear)
  const u16* gA[4];
#pragma unroll
  for (int ch = 0; ch < 4; ++ch) {
    int row  = ch * 64 + (tid >> 3);
    int scol = ((tid & 7) ^ (row & 7)) << 3;
    gA[ch] = A + (bm0 + row) * (size_t)K + scol;
  }
  const u16* gB[BCH];
#pragma unroll
  for (int ch = 0; ch < BCH; ++ch) {
    int row  = ch * 64 + (tid >> 3);
    int scol = ((tid & 7) ^ (row & 7)) << 3;
    gB[ch] = Bt + (bn0 + row) * (size_t)K + scol;
  }

  // LDS byte addresses for asm ds_read: [buf][kk], swizzled col term per lane
  unsigned aA[2][2], aB[2][2];
  {
    const unsigned base0 = lds_addr(lds);
    const unsigned rowA = (unsigned)(wm * 128 + llo) * 128u;
    const unsigned rowB = (unsigned)(wn * (NF * 16) + llo) * 128u;
    const unsigned msk = (unsigned)((llo & 7) << 4);
#pragma unroll
    for (int bf = 0; bf < 2; ++bf)
#pragma unroll
      for (int kk = 0; kk < 2; ++kk) {
        unsigned colk = ((unsigned)(kk * 64 + lhi * 16)) ^ msk;
        aA[bf][kk] = base0 + (unsigned)bf * (BUFS * 2) + rowA + colk;
        aB[bf][kk] = base0 + (unsigned)bf * (BUFS * 2) + (ASZ * 2) + rowB + colk;
      }
  }

#define SGA(t, bsel, ch) __builtin_amdgcn_global_load_lds(                       \
    (const AS1 void*)(gA[ch] + ((size_t)(t) << 6)),                              \
    (AS3 void*)(lds + (bsel) * BUFS + (ch) * 4096 + wave * 512), 16, 0, 0)
#define SGB(t, bsel, ch) __builtin_amdgcn_global_load_lds(                       \
    (const AS1 void*)(gB[ch] + ((size_t)(t) << 6)),                              \
    (AS3 void*)(lds + (bsel) * BUFS + ASZ + (ch) * 4096 + wave * 512), 16, 0, 0)

  f32x4 acc[8][NF] = {};
  bf16x8 bfr[2][4];

#define PHASE(BUF, MH, KK, RDB, STG, WC)                                         \
  {                                                                              \
    bf16x8 af[4];                                                                \
    af[0] = dsr<(MH) * 8192 + 0>(aA[BUF][KK]);                                   \
    af[1] = dsr<(MH) * 8192 + 2048>(aA[BUF][KK]);                                \
    af[2] = dsr<(MH) * 8192 + 4096>(aA[BUF][KK]);                                \
    af[3] = dsr<(MH) * 8192 + 6144>(aA[BUF][KK]);                                \
    if (RDB) {                                                                   \
      bfr[KK][0] = dsr<0>(aB[BUF][KK]);                                          \
      bfr[KK][1] = dsr<2048>(aB[BUF][KK]);                                       \
      if (NF == 4) {                                                             \
        bfr[KK][2] = dsr<4096>(aB[BUF][KK]);                                     \
        bfr[KK][3] = dsr<6144>(aB[BUF][KK]);                                     \
      }                                                                          \
    }                                                                            \
    STG;                                                                         \
    asm volatile("s_barrier" ::: "memory");                                      \
    asm volatile("s_waitcnt lgkmcnt(0)" ::: "memory");                           \
    __builtin_amdgcn_sched_barrier(0);                                           \
    __builtin_amdgcn_s_setprio(1);                                               \
    _Pragma("unroll") for (int m = 0; m < 4; ++m)                                \
      _Pragma("unroll") for (int n = 0; n < NF; ++n)                             \
        acc[(MH) * 4 + m][n] = __builtin_amdgcn_mfma_f32_16x16x32_bf16(          \
            af[m], bfr[KK][n], acc[(MH) * 4 + m][n], 0, 0, 0);                   \
    __builtin_amdgcn_s_setprio(0);                                               \
    WC;                                                                          \
    asm volatile("s_barrier" ::: "memory");                                      \
  }

  // prologue: tile0 full -> buf0; tile1 first half -> buf1
  SGA(0, 0, 0); SGA(0, 0, 2); SGB(0, 0, 0); SGB(0, 0, 1);
  if (BCH == 4) { SGB(0, 0, 2); SGB(0, 0, 3); }
  SGA(0, 0, 1); SGA(0, 0, 3);
  SGA(1, 1, 0); SGA(1, 1, 2); SGB(1, 1, 0); SGB(1, 1, 1);
  asm volatile("s_waitcnt vmcnt(4)" ::: "memory");
  asm volatile("s_barrier" ::: "memory");

  for (int u = 0; u < NT; u += 2) {
    const int v = u + 1;
    // ---- phases 0-3: tile u from buf0 ----
    PHASE(0, 0, 0, true,
          ({ if (BCH == 4) { SGB(v, 1, 2); SGB(v, 1, 3); } else { SGA(v, 1, 1); SGA(v, 1, 3); } }),
          ((void)0));
    PHASE(0, 0, 1, true,
          ({ if (BCH == 4) { SGA(v, 1, 1); SGA(v, 1, 3); } }),
          ((void)0));
    PHASE(0, 1, 0, false,
          ({ if (u + 2 < NT) { SGA(u + 2, 0, 0); SGA(u + 2, 0, 2); } }),
          ((void)0));
    PHASE(0, 1, 1, false,
          ({ if (u + 2 < NT) { SGB(u + 2, 0, 0); SGB(u + 2, 0, 1); } }),
          ({ if (u + 2 < NT) asm volatile("s_waitcnt vmcnt(4)" ::: "memory");
             else            asm volatile("s_waitcnt vmcnt(0)" ::: "memory"); }));
    // ---- phases 4-7: tile v from buf1 ----
    PHASE(1, 0, 0, true,
          ({ if (u + 2 < NT) { if (BCH == 4) { SGB(u + 2, 0, 2); SGB(u + 2, 0, 3); }
                               else          { SGA(u + 2, 0, 1); SGA(u + 2, 0, 3); } } }),
          ((void)0));
    PHASE(1, 0, 1, true,
          ({ if (u + 2 < NT && BCH == 4) { SGA(u + 2, 0, 1); SGA(u + 2, 0, 3); } }),
          ((void)0));
    PHASE(1, 1, 0, false,
          ({ if (v + 2 < NT) { SGA(v + 2, 1, 0); SGA(v + 2, 1, 2); } }),
          ((void)0));
    PHASE(1, 1, 1, false,
          ({ if (v + 2 < NT) { SGB(v + 2, 1, 0); SGB(v + 2, 1, 1); } }),
          ({ if (v + 2 < NT) asm volatile("s_waitcnt vmcnt(4)" ::: "memory");
             else            asm volatile("s_waitcnt vmcnt(0)" ::: "memory"); }));
  }
#undef PHASE
#undef SGA
#undef SGB

  // epilogue: C mapping col = n*16+llo, row = 16*frag + lhi*4 + r
#pragma unroll
  for (int am = 0; am < 8; ++am) {
    const int mh = am >> 2, m = am & 3;
    const int rowb = (int)bm0 + wm * 128 + mh * 64 + m * 16 + lhi * 4;
#pragma unroll
    for (int n = 0; n < NF; ++n) {
      const int col = (int)bn0 + wn * (16 * NF) + n * 16 + llo;
#pragma unroll
      for (int r = 0; r < 4; ++r) {
        float v = acc[am][n][r];
        size_t idx = (size_t)(rowb + r) * N + col;
        if (EPI == 0) {
          ((u16*)outp)[idx] = f2bf(v);
        } else if (EPI == 1) {
          float xb = v + bias[col];
          float sp = (xb > 20.f) ? xb : log1pf(__expf(xb));  // softplus
          ((u16*)outp)[idx] = f2bf(sp);
        } else {
          ((float*)outp)[idx] = v;
        }
      }
    }
  }
}

// ---------------- causal depthwise conv (K=4) + SiLU, 4 d per thread ----------------
__global__ void conv_silu4(const u16* __restrict__ xz, const float* __restrict__ w,
                           const float* __restrict__ cb, u16* __restrict__ xs, int total4) {
  int idx = blockIdx.x * 256 + threadIdx.x;
  if (idx >= total4) return;
  int d4 = idx & (DINNER / 4 - 1);
  int l  = (idx >> 9) & (SEQLEN - 1);
  int b  = idx >> 20;
  int d  = d4 * 4;
  float4 wv[4];
#pragma unroll
  for (int j = 0; j < 4; ++j) wv[j] = ((const float4*)w)[d + j];
  float4 bias = *(const float4*)(cb + d);
  float acc[4] = { bias.x, bias.y, bias.z, bias.w };
#pragma unroll
  for (int k = 0; k < 4; ++k) {
    int li = l - 3 + k;
    if (li >= 0) {
      ushort4 xv = *(const ushort4*)(xz + (size_t)(b * SEQLEN + li) * (2 * DINNER) + d);
      acc[0] = fmaf((&wv[0].x)[k], bf2f(xv.x), acc[0]);
      acc[1] = fmaf((&wv[1].x)[k], bf2f(xv.y), acc[1]);
      acc[2] = fmaf((&wv[2].x)[k], bf2f(xv.z), acc[2]);
      acc[3] = fmaf((&wv[3].x)[k], bf2f(xv.w), acc[3]);
    }
  }
  ushort4 o;
  o.x = f2bf(acc[0] / (1.f + __expf(-acc[0])));
  o.y = f2bf(acc[1] / (1.f + __expf(-acc[1])));
  o.z = f2bf(acc[2] / (1.f + __expf(-acc[2])));
  o.w = f2bf(acc[3] / (1.f + __expf(-acc[3])));
  *(ushort4*)(xs + (size_t)idx * 4) = o;
}

// ---------------- x-projection: xproj(ROWS x 32) = xs(ROWS x 2048) @ Wx(2048 x 32) ----------------
__global__ void xproj_kernel(const u16* __restrict__ xs, const float* __restrict__ Wx,
                             float* __restrict__ outp) {
  __shared__ float part[256];
  int row = blockIdx.x;
  int tid = threadIdx.x;
  int c = tid & 31, kp = tid >> 5;
  const u16* xr = xs + (size_t)row * DINNER + kp * 256;
  const float* wp = Wx + (size_t)(kp * 256) * 32 + c;
  float acc = 0.f;
#pragma unroll 4
  for (int kk = 0; kk < 32; ++kk) {
    u16x8 xv = *(const u16x8*)(const void*)(xr + kk * 8);
#pragma unroll
    for (int j = 0; j < 8; ++j)
      acc = fmaf(bf2f(xv[j]), wp[(kk * 8 + j) * 32], acc);
  }
  part[tid] = acc;
  __syncthreads();
  if (tid < 32) {
    float s = 0.f;
#pragma unroll
    for (int p = 0; p < 8; ++p) s += part[p * 32 + tid];
    outp[(size_t)row * 32 + tid] = s;
  }
}

// ---------------- chunked selective scan v3 (unchanged from R5) ----------------
#define SC_NC 32                // chunks
#define SC_CL 64                // steps per chunk
#define SC_LDS (2 * SC_NC * 16 * 33 * 4)   // 135168 B

__launch_bounds__(512, 1)
__global__ void scan_v3(const u16* __restrict__ delta, const u16* __restrict__ xs,
                        const float* __restrict__ xproj, const u16* __restrict__ xz,
                        const float* __restrict__ A_log, const float* __restrict__ Dp,
                        u16* __restrict__ yg) {
  extern __shared__ float smem[];
  float* cP = smem;
  float* cH = smem + SC_NC * 16 * 33;
  const int tid = threadIdx.x;
  const int dl = tid & 15, ck = tid >> 4;
  const int b = blockIdx.x >> 6, dblk = blockIdx.x & 63;
  const int d0 = dblk * 32 + dl * 2;
  const int r0 = b * SEQLEN + ck * SC_CL;

  float A0[DSTATE], A1[DSTATE];
  {
    const f32x4* ap0 = (const f32x4*)(A_log + (size_t)d0 * DSTATE);
    const f32x4* ap1 = (const f32x4*)(A_log + (size_t)(d0 + 1) * DSTATE);
#pragma unroll
    for (int q = 0; q < 4; ++q) {
      f32x4 a0 = ap0[q], a1 = ap1[q];
#pragma unroll
      for (int j = 0; j < 4; ++j) { A0[q * 4 + j] = -__expf(a0[j]); A1[q * 4 + j] = -__expf(a1[j]); }
    }
  }

  const u32* dP = (const u32*)(delta + (size_t)r0 * DINNER + d0);
  const u32* xP = (const u32*)(xs    + (size_t)r0 * DINNER + d0);
  const u32* zP = (const u32*)(xz + (size_t)r0 * (2 * DINNER) + DINNER + d0);
  const float* bP = xproj + (size_t)r0 * 32;
  const int DW = DINNER / 2;
  const int ZW = DINNER;

  float P0[DSTATE], P1[DSTATE], H0[DSTATE], H1[DSTATE];
#pragma unroll
  for (int s = 0; s < DSTATE; ++s) { P0[s] = P1[s] = 1.f; H0[s] = H1[s] = 0.f; }
  {
    u32 dq0 = dP[0], xq0 = xP[0];
    u32 dq1 = dP[DW], xq1 = xP[DW];
    f32x4 Bn[4];
#pragma unroll
    for (int q = 0; q < 4; ++q) Bn[q] = ((const f32x4*)bP)[q];
    for (int l = 0; l < SC_CL; ++l) {
      const u32 dc = dq0, xc = xq0;
      dq0 = dq1; xq0 = xq1;
      if (l + 2 < SC_CL) { dq1 = dP[(l + 2) * DW]; xq1 = xP[(l + 2) * DW]; }
      f32x4 Bc[4] = { Bn[0], Bn[1], Bn[2], Bn[3] };
      if (l + 1 < SC_CL) {
        const f32x4* bn = (const f32x4*)(bP + (l + 1) * 32);
#pragma unroll
        for (int q = 0; q < 4; ++q) Bn[q] = bn[q];
      }
      float dt0 = bflo(dc), dt1 = bfhi(dc);
      float x0 = bflo(xc),  x1 = bfhi(xc);
      float dtx0 = dt0 * x0, dtx1 = dt1 * x1;
#pragma unroll
      for (int s = 0; s < DSTATE; ++s) {
        float bs = Bc[s >> 2][s & 3];
        float dA0 = fmaf(A0[s], dt0, 1.f);
        float dA1 = fmaf(A1[s], dt1, 1.f);
        P0[s] *= dA0; P1[s] *= dA1;
        H0[s] = fmaf(H0[s], dA0, bs * dtx0);
        H1[s] = fmaf(H1[s], dA1, bs * dtx1);
      }
    }
  }
  {
    float* p = cP + (ck * 16 + dl) * 33;
    float* h = cH + (ck * 16 + dl) * 33;
#pragma unroll
    for (int s = 0; s < DSTATE; ++s) {
      p[s] = P0[s]; p[16 + s] = P1[s];
      h[s] = H0[s]; h[16 + s] = H1[s];
    }
  }
  __syncthreads();

  {
    const int s2 = tid & 15, dd = tid >> 4;
    const int idx = (dd & 1) * 16 + s2;
    float* pbase = cP + (dd >> 1) * 33 + idx;
    float* hbase = cH + (dd >> 1) * 33 + idx;
    float h = 0.f;
    for (int c = 0; c < SC_NC; ++c) {
      float p = pbase[c * 16 * 33], hh = hbase[c * 16 * 33];
      pbase[c * 16 * 33] = h;
      h = fmaf(p, h, hh);
    }
  }
  __syncthreads();

  float h0[DSTATE], h1[DSTATE];
  {
    const float* p = cP + (ck * 16 + dl) * 33;
#pragma unroll
    for (int s = 0; s < DSTATE; ++s) { h0[s] = p[s]; h1[s] = p[16 + s]; }
  }
  const float Dv0 = Dp[d0], Dv1 = Dp[d0 + 1];
  u32* yP = (u32*)(yg + (size_t)r0 * DINNER + d0);
  {
    u32 dq0 = dP[0], xq0 = xP[0], zq0 = zP[0];
    u32 dq1 = dP[DW], xq1 = xP[DW], zq1 = zP[ZW];
    f32x4 Bn[4], Cn[4];
#pragma unroll
    for (int q = 0; q < 4; ++q) { Bn[q] = ((const f32x4*)bP)[q]; Cn[q] = ((const f32x4*)bP)[q + 4]; }
    for (int l = 0; l < SC_CL; ++l) {
      const u32 dc = dq0, xc = xq0, zc = zq0;
      dq0 = dq1; xq0 = xq1; zq0 = zq1;
      if (l + 2 < SC_CL) { dq1 = dP[(l + 2) * DW]; xq1 = xP[(l + 2) * DW]; zq1 = zP[(l + 2) * ZW]; }
      f32x4 Bc[4] = { Bn[0], Bn[1], Bn[2], Bn[3] };
      f32x4 Cc[4] = { Cn[0], Cn[1], Cn[2], Cn[3] };
      if (l + 1 < SC_CL) {
        const f32x4* bn = (const f32x4*)(bP + (l + 1) * 32);
#pragma unroll
        for (int q = 0; q < 4; ++q) { Bn[q] = bn[q]; Cn[q] = bn[q + 4]; }
      }
      float dt0 = bflo(dc), dt1 = bfhi(dc);
      float x0 = bflo(xc),  x1 = bfhi(xc);
      float dtx0 = dt0 * x0, dtx1 = dt1 * x1;
      float yp0 = 0.f, yp1 = 0.f;
#pragma unroll
      for (int s = 0; s < DSTATE; ++s) {
        float bs = Bc[s >> 2][s & 3];
        float cs = Cc[s >> 2][s & 3];
        float dA0 = fmaf(A0[s], dt0, 1.f);
        float dA1 = fmaf(A1[s], dt1, 1.f);
        h0[s] = fmaf(h0[s], dA0, bs * dtx0);
        h1[s] = fmaf(h1[s], dA1, bs * dtx1);
        yp0 = fmaf(h0[s], cs, yp0);
        yp1 = fmaf(h1[s], cs, yp1);
      }
      float z0 = bflo(zc), z1 = bfhi(zc);
      float y0 = (yp0 + Dv0 * x0) * (z0 / (1.f + __expf(-z0)));
      float y1 = (yp1 + Dv1 * x1) * (z1 / (1.f + __expf(-z1)));
      yP[l * DW] = (u32)f2bf(y0) | ((u32)f2bf(y1) << 16);
    }
  }
}

extern "C" void kernel_launch(void* const* d_in, const int* in_sizes, int n_in,
                              void* d_out, int out_size, void* d_ws, size_t ws_size,
                              hipStream_t stream) {
  const float* x       = (const float*)d_in[0];
  const float* W_in    = (const float*)d_in[1];
  const float* conv_w  = (const float*)d_in[2];
  const float* conv_b  = (const float*)d_in[3];
  const float* W_xproj = (const float*)d_in[4];
  const float* W_dt    = (const float*)d_in[5];
  const float* b_dt    = (const float*)d_in[6];
  const float* A_log   = (const float*)d_in[7];
  const float* D_param = (const float*)d_in[8];
  const float* W_out   = (const float*)d_in[9];
  float* out = (float*)d_out;

  char* ws = (char*)d_ws;
  const size_t MB = 1ull << 20;
  u16*   x_bf  = (u16*)(ws);              // 16 MB   [dead after GEMM1]
  u16*   WinT  = (u16*)(ws + 16 * MB);    //  8 MB   [dead after GEMM1]
  u16*   WdtT  = (u16*)(ws + 24 * MB);    //  8 MB   [dead after GEMM2]
  u16*   xz_bf = (u16*)(ws + 32 * MB);    // 64 MB   [live through scan]
  u16*   xs_bf = (u16*)(ws + 96 * MB);    // 32 MB   [live through scan]
  u16*   delta = (u16*)(ws + 128 * MB);   // 32 MB (bf16)
  float* xpj   = (float*)(ws + 192 * MB); //  1 MB
  u16*   WoutT = (u16*)(ws + 193 * MB);   //  4 MB
  u16*   yg    = (u16*)(ws);              // 32 MB, aliases x_bf/WinT/WdtT (dead by then)

  hipFuncSetAttribute((const void*)gemm8p<0, 256>, hipFuncAttributeMaxDynamicSharedMemorySize, 131072);
  hipFuncSetAttribute((const void*)gemm8p<1, 256>, hipFuncAttributeMaxDynamicSharedMemorySize, 131072);
  hipFuncSetAttribute((const void*)gemm8p<2, 128>, hipFuncAttributeMaxDynamicSharedMemorySize, 98304);
  hipFuncSetAttribute((const void*)scan_v3, hipFuncAttributeMaxDynamicSharedMemorySize, SC_LDS);

  dim3 tb(32, 8);

  // 1) casts / weight transposes
  cast_f32_bf16<<<(ROWS * DMODEL / 4 + 255) / 256, 256, 0, stream>>>(x, x_bf, ROWS * DMODEL / 4);
  transpose_cast<<<dim3((2 * DINNER) / 32, DMODEL / 32), tb, 0, stream>>>(W_in, WinT, DMODEL, 2 * DINNER);
  transpose_cast<<<dim3(DINNER / 32, DINNER / 32), tb, 0, stream>>>(W_dt, WdtT, DINNER, DINNER);
  transpose_cast<<<dim3(DMODEL / 32, DINNER / 32), tb, 0, stream>>>(W_out, WoutT, DINNER, DMODEL);

  // 2) xz = x @ W_in   (8192 x 4096, K=1024) -> bf16. grid 512, XCD tile 8x8
  gemm8p<0, 256><<<512, 512, 131072, stream>>>(x_bf, WinT, xz_bf, nullptr,
                                               ROWS, 2 * DINNER, DMODEL, 16, 8, 8);

  // 3) xs = silu(causal_conv(xc) + conv_b) -> bf16 (4 d per thread)
  conv_silu4<<<(ROWS * DINNER / 4) / 256, 256, 0, stream>>>(
      xz_bf, conv_w, conv_b, xs_bf, ROWS * DINNER / 4);

  // 4) delta = softplus(xs @ W_dt + b_dt) (8192 x 2048, K=2048) -> bf16. grid 256, XCD tile 4x8
  gemm8p<1, 256><<<256, 512, 131072, stream>>>(xs_bf, WdtT, delta, b_dt,
                                               ROWS, DINNER, DINNER, 8, 4, 8);

  // 5) [Bs|Cs] = xs @ W_xproj   (8192 x 32) -> f32
  xproj_kernel<<<ROWS, 256, 0, stream>>>(xs_bf, W_xproj, xpj);

  // 6) chunked selective scan v3 + D-skip + silu(z) gate -> yg bf16
  scan_v3<<<BATCH * (DINNER / 32), 512, SC_LDS, stream>>>(
      delta, xs_bf, xpj, xz_bf, A_log, D_param, yg);

  // 7) out = yg @ W_out  (8192 x 1024, K=2048) -> f32. BN=128, grid 256, XCD tile 4x8
  gemm8p<2, 128><<<256, 512, 98304, stream>>>(yg, WoutT, out, nullptr,
                                              ROWS, DMODEL, DINNER, 8, 4, 8);
}